// Round 3
// baseline (420.063 us; speedup 1.0000x reference)
//
#include <hip/hip_runtime.h>
#include <cmath>

// ---------------------------------------------------------------------------
// EncoderLayer: x -> MHA -> +res -> LN1 -> FFN(GELU) -> +res -> LN2
// B=2 L=2048 D=1024 H=16 dk=64 F=4096  (M = B*L = 4096 rows)
// bf16 MFMA 16x16x32, fp32 accumulate, fp32 LN/residual.
//
// Round 3 changes:
//  * attn: P^T LDS bounce replaced by in-register redistribution (one
//    shfl_xor(16) pair per kh; V-operand segment permutation sV=bitrev2(quad)
//    makes the exchange minimal). LDS 50K->32K, __launch_bounds__(256,4)
//    -> 4 blocks/CU. Removes P bank conflicts + lgkm drain.
//  * Wo projection: legacy 128x64 kernel -> gemm256 split-K=4 (256 blocks),
//    fp32 partial slabs on dead workspace, reduced in ln4b_k (which now
//    serves both LN1 (fp32+bf16 out) and LN2).
// ---------------------------------------------------------------------------

typedef unsigned short u16;
typedef unsigned int u32;
typedef __attribute__((ext_vector_type(8))) __bf16 bf16x8;
typedef __attribute__((ext_vector_type(4))) float f32x4;

#define MFMA16(a, b, c) __builtin_amdgcn_mfma_f32_16x16x32_bf16(a, b, c, 0, 0, 0)

__device__ __forceinline__ u16 f2bf(float f) {
  u32 u = __builtin_bit_cast(u32, f);
  u += 0x7fffu + ((u >> 16) & 1u);   // round-to-nearest-even
  return (u16)(u >> 16);
}

// truncation-pack two fp32 -> bf16x2 in ONE v_perm_b32
__device__ __forceinline__ u32 packtrunc(float lo, float hi) {
#if __has_builtin(__builtin_amdgcn_perm)
  return __builtin_amdgcn_perm(__builtin_bit_cast(u32, hi),
                               __builtin_bit_cast(u32, lo), 0x07060302u);
#else
  return (__builtin_bit_cast(u32, lo) >> 16) |
         (__builtin_bit_cast(u32, hi) & 0xFFFF0000u);
#endif
}

__device__ __forceinline__ bf16x8 ld_frag(const u16* p) {
  return __builtin_bit_cast(bf16x8, *(const uint4*)p);
}

__device__ __forceinline__ float fexp2(float x) {
#if __has_builtin(__builtin_amdgcn_exp2f)
  return __builtin_amdgcn_exp2f(x);
#else
  return exp2f(x);
#endif
}

// async global->LDS, 16B per lane; LDS dest = wave-uniform base + lane*16
__device__ __forceinline__ void gload16(const u16* g, u16* l) {
  __builtin_amdgcn_global_load_lds(
      (const __attribute__((address_space(1))) void*)g,
      (__attribute__((address_space(3))) void*)l, 16, 0, 0);
}

// counted waits: gate vmem retirement without draining the pipeline, and
// drain own LDS reads before buffer-recycling barriers.
#define WAITVL(N) asm volatile("s_waitcnt vmcnt(" #N ") lgkmcnt(0)" ::: "memory")
#define BAR() do { __builtin_amdgcn_s_barrier(); asm volatile("" ::: "memory"); } while (0)

// ---------------- fp32 -> bf16 elementwise convert (x) ----------------------
__global__ __launch_bounds__(256) void cvt_bf16_k(const float* __restrict__ src,
                                                  u16* __restrict__ dst) {
  int i = (blockIdx.x * 256 + threadIdx.x) * 4;
  float4 v = *(const float4*)(src + i);
  ushort4 o;
  o.x = f2bf(v.x); o.y = f2bf(v.y); o.z = f2bf(v.z); o.w = f2bf(v.w);
  *(ushort4*)(dst + i) = o;
}

// ---------------- fp32 [R][C] -> bf16 [C][R] transpose ----------------------
__global__ __launch_bounds__(256) void transpose_bf16_k(const float* __restrict__ src,
                                                        u16* __restrict__ dst,
                                                        int R, int C) {
  __shared__ float tile[32][33];
  int tx = threadIdx.x & 31, ty = threadIdx.x >> 5;  // 32 x 8
  int c0 = blockIdx.x * 32, r0 = blockIdx.y * 32;
#pragma unroll
  for (int i = 0; i < 4; i++)
    tile[ty + 8 * i][tx] = src[(long)(r0 + ty + 8 * i) * C + c0 + tx];
  __syncthreads();
#pragma unroll
  for (int i = 0; i < 4; i++)
    dst[(long)(c0 + ty + 8 * i) * R + r0 + tx] = f2bf(tile[tx][ty + 8 * i]);
}

// ---- 4x 1024x1024 fp32 -> bf16 transposes in one launch (z picks matrix) ---
__global__ __launch_bounds__(256) void transpose4_bf16_k(
    const float* __restrict__ Wq, const float* __restrict__ Wk,
    const float* __restrict__ Wv, const float* __restrict__ Wo,
    u16* __restrict__ wqkvT, u16* __restrict__ woT) {
  const int z = blockIdx.z;
  const float* src = (z == 0) ? Wq : (z == 1) ? Wk : (z == 2) ? Wv : Wo;
  u16* dst = (z < 3) ? (wqkvT + (size_t)z * 1024 * 1024) : woT;
  __shared__ float tile[32][33];
  int tx = threadIdx.x & 31, ty = threadIdx.x >> 5;
  int c0 = blockIdx.x * 32, r0 = blockIdx.y * 32;
#pragma unroll
  for (int i = 0; i < 4; i++)
    tile[ty + 8 * i][tx] = src[(long)(r0 + ty + 8 * i) * 1024 + c0 + tx];
  __syncthreads();
#pragma unroll
  for (int i = 0; i < 4; i++)
    dst[(long)(c0 + ty + 8 * i) * 1024 + r0 + tx] = f2bf(tile[tx][ty + 8 * i]);
}

// ---------------------------------------------------------------------------
// gemm256: C[M][N] = A[M][K] * BT[N][K]^T, 256x256 block tile, BK=32,
// 8 waves (2 wm x 4 wn), per-wave 128x64 output (8 m-frags x 4 n-frags).
// LDS: 4-deep ring of (A 256x32 + B 256x32) bf16 = 4 x 32 KiB = 128 KiB.
// Staging of K-tile t happens at tile t-3 (prologue covers tiles 0..2).
// Tile-top gate: s_waitcnt vmcnt(8) + lgkmcnt(0) + s_barrier; buffer
// (t+3)&3 == (t-1)&3 is free when staged. No vmcnt(0) in the main loop.
// Each K-tile = 2 barrier-sandwiched phases of 16 MFMA (role-split).
// MODE 0: QKV scatter; MODE 2: GELU->bf16; MODE 3: fp32 partial slab (kz).
// ---------------------------------------------------------------------------
template <int MODE>
__global__ __launch_bounds__(512, 2) void gemm256_k(
    const u16* __restrict__ A, const u16* __restrict__ BT,
    int N, int lda, int ldb, int Kc,
    const float* __restrict__ bias, float* __restrict__ outF, u16* __restrict__ outB,
    float* __restrict__ p1, float* __restrict__ p2, float* __restrict__ p3,
    u16* __restrict__ qd, u16* __restrict__ kd, u16* __restrict__ vTd,
    const float* __restrict__ bq, const float* __restrict__ bk, const float* __restrict__ bv) {
  __shared__ u16 As[4][256 * 32];   // 64 KiB
  __shared__ u16 Bs[4][256 * 32];   // 64 KiB
  const int tid = threadIdx.x;
  const int wave = tid >> 6, lane = tid & 63, quad = lane >> 4, l16 = lane & 15;
  const int wm = wave >> 2, wn = wave & 3;
  const int m0 = blockIdx.y * 256, n0 = blockIdx.x * 256;
  const int kz = blockIdx.z;
  const long kofs = (long)kz * Kc;
  const int KT = Kc >> 5;

  // staging: one gload issue = 16 rows x 64B; lane -> row lane>>2, seg lane&3;
  // global source seg pre-XORed so linear LDS + XOR read line up (rule #21).
  const int srow = lane >> 2;
  const int sseg = (lane & 3) ^ (srow & 3);
  const u16* aS = A + (long)(m0 + wave * 32 + srow) * lda + kofs + sseg * 8;
  const u16* bS = BT + (long)(n0 + wave * 32 + srow) * ldb + kofs + sseg * 8;

  auto stageA = [&](int sb, int s) {
    const u16* p = aS + (long)s * 32;
    gload16(p, &As[sb][wave * 1024]);
    gload16(p + 16 * (long)lda, &As[sb][wave * 1024 + 512]);
  };
  auto stageB = [&](int sb, int s) {
    const u16* p = bS + (long)s * 32;
    gload16(p, &Bs[sb][wave * 1024]);
    gload16(p + 16 * (long)ldb, &Bs[sb][wave * 1024 + 512]);
  };

  // fragment read offsets (u16 units): row*32 + ((quad ^ (row&3)) * 8)
  int aro[8], bro[4];
#pragma unroll
  for (int mf = 0; mf < 8; mf++) {
    int r = wm * 128 + mf * 16 + l16;
    aro[mf] = r * 32 + ((quad ^ (r & 3)) * 8);
  }
#pragma unroll
  for (int nf = 0; nf < 4; nf++) {
    int r = wn * 64 + nf * 16 + l16;
    bro[nf] = r * 32 + ((quad ^ (r & 3)) * 8);
  }

  f32x4 acc[8][4] = {};

  // prologue: stage tiles 0,1,2 (12 vmem ops in flight)
  stageA(0, 0); stageB(0, 0);
  stageA(1, 1); stageB(1, 1);
  stageA(2, 2); stageB(2, 2);

#pragma unroll 1
  for (int t = 0; t < KT; ++t) {
    const int buf = t & 3;
    // gate: tile t's loads retired (mine); everyone's via the barrier.
    if (t < KT - 2)      { WAITVL(8); }
    else if (t == KT - 2){ WAITVL(4); }
    else                 { WAITVL(0); }
    BAR();

    // ---- phase 1: frag reads + stage A(t+3); BAR; MFMA m0..3 ----
    bf16x8 af[4], bf4[4];
#pragma unroll
    for (int i = 0; i < 4; i++) af[i] = ld_frag(&As[buf][aro[i]]);
#pragma unroll
    for (int i = 0; i < 4; i++) bf4[i] = ld_frag(&Bs[buf][bro[i]]);
    if (t + 3 < KT) stageA((t + 3) & 3, t + 3);
    BAR();
    __builtin_amdgcn_s_setprio(1);
#pragma unroll
    for (int mf = 0; mf < 4; mf++)
#pragma unroll
      for (int nf = 0; nf < 4; nf++)
        acc[mf][nf] = MFMA16(af[mf], bf4[nf], acc[mf][nf]);
    __builtin_amdgcn_s_setprio(0);

    // ---- phase 2: frag reads + stage B(t+3); BAR; MFMA m4..7 ----
    bf16x8 ag[4];
#pragma unroll
    for (int i = 0; i < 4; i++) ag[i] = ld_frag(&As[buf][aro[4 + i]]);
    if (t + 3 < KT) stageB((t + 3) & 3, t + 3);
    BAR();
    __builtin_amdgcn_s_setprio(1);
#pragma unroll
    for (int mf = 0; mf < 4; mf++)
#pragma unroll
      for (int nf = 0; nf < 4; nf++)
        acc[4 + mf][nf] = MFMA16(ag[mf], bf4[nf], acc[4 + mf][nf]);
    __builtin_amdgcn_s_setprio(0);
  }

  // ---------------- epilogues ----------------
  if (MODE == 0) {
    const int nbase = n0 + wn * 64;            // wave-uniform
    const int mat = nbase >> 10;               // 0=q 1=k 2=v
    const float* bp = (mat == 0) ? bq : ((mat == 1) ? bk : bv);
    float bb[4];
    int hh0[4], dd0[4];
#pragma unroll
    for (int nf = 0; nf < 4; nf++) {
      int nn = (nbase + nf * 16 + l16) & 1023;
      bb[nf] = bp[nn];
      hh0[nf] = nn >> 6;
      dd0[nf] = nn & 63;
    }
    if (mat < 2) {
#pragma unroll
      for (int mf = 0; mf < 8; mf++) {
#pragma unroll
        for (int r = 0; r < 4; r++) {
          int mr = m0 + wm * 128 + mf * 16 + quad * 4 + r;
          int bI = mr >> 11, ll = mr & 2047;
#pragma unroll
          for (int nf = 0; nf < 4; nf++) {
            float v = acc[mf][nf][r] + bb[nf];
            long idx = ((long)((bI * 16 + hh0[nf]) * 2048 + ll)) * 64 + dd0[nf];
            if (mat == 0) {
              // fold 1/sqrt(dk)*log2(e) so attention uses exp2 directly
              qd[idx] = f2bf(v * 0.18033688011112043f);
            } else {
              kd[idx] = f2bf(v);
            }
          }
        }
      }
    } else {
#pragma unroll
      for (int nf = 0; nf < 4; nf++) {
#pragma unroll
        for (int mf = 0; mf < 8; mf++) {
#pragma unroll
          for (int r = 0; r < 4; r++) {
            int mr = m0 + wm * 128 + mf * 16 + quad * 4 + r;
            int bI = mr >> 11, ll = mr & 2047;
            float v = acc[mf][nf][r] + bb[nf];
            vTd[((long)((bI * 16 + hh0[nf]) * 64 + dd0[nf])) * 2048 + ll] = f2bf(v);
          }
        }
      }
    }
  } else if (MODE == 2) {
    float bb[4];
#pragma unroll
    for (int nf = 0; nf < 4; nf++) bb[nf] = bias[n0 + wn * 64 + nf * 16 + l16];
#pragma unroll
    for (int mf = 0; mf < 8; mf++) {
#pragma unroll
      for (int r = 0; r < 4; r++) {
        int mr = m0 + wm * 128 + mf * 16 + quad * 4 + r;
        u16* orow = outB + (long)mr * N + n0 + wn * 64 + l16;
#pragma unroll
        for (int nf = 0; nf < 4; nf++) {
          float v = acc[mf][nf][r] + bb[nf];
          v = 0.5f * v * (1.0f + erff(v * 0.70710678118654752f));  // exact GELU
          orow[nf * 16] = f2bf(v);
        }
      }
    }
  } else {  // MODE 3: fp32 partial slab per kz (bias folded into LN reduce)
    float* sl = (kz == 0) ? outF : (kz == 1) ? p1 : (kz == 2) ? p2 : p3;
#pragma unroll
    for (int mf = 0; mf < 8; mf++) {
#pragma unroll
      for (int r = 0; r < 4; r++) {
        int mr = m0 + wm * 128 + mf * 16 + quad * 4 + r;
        float* orow = sl + (long)mr * N + n0 + wn * 64 + l16;
#pragma unroll
        for (int nf = 0; nf < 4; nf++) orow[nf * 16] = acc[mf][nf][r];
      }
    }
  }
}

// ---------------- flash attention (S^T, LDS-staged K/V, key-split 2) --------
// grid (L/128, B*H, 2), 4 waves; wave owns 32 q rows (two 16-q sets); 64-key
// chunks over this block's 1024-key half. P^T kept in registers: after
// S^T = K Q^T, even quads keep the f-low packed words, odd quads keep f-high;
// one shfl_xor(16) pair per kh completes the B-fragment. V A-operand reads
// segment sV = bitrev2(quad) so A/B key order matches.
// Partial unnormalized O (fp32) + per-row (m,l) to workspace; combined later.
__global__ __launch_bounds__(256, 4) void attn_k(const u16* __restrict__ qd,
                                                 const u16* __restrict__ kd,
                                                 const u16* __restrict__ vTd,
                                                 float* __restrict__ oP0,
                                                 float* __restrict__ oP1,
                                                 float* __restrict__ ml0,
                                                 float* __restrict__ ml1) {
  __shared__ u16 Ks[2][64 * 64];
  __shared__ u16 Vs[2][64 * 64];
  const int tid = threadIdx.x;
  const int wave = tid >> 6, lane = tid & 63, quad = lane >> 4, l16 = lane & 15;
  const int bh = blockIdx.y;
  const int kz = blockIdx.z;
  const int jbeg = kz * 1024, jend = jbeg + 1024;
  const u16* Q = qd + (long)bh * 2048 * 64;
  const u16* Kp = kd + (long)bh * 2048 * 64;
  const u16* Vt = vTd + (long)bh * 64 * 2048;
  const int qbase = blockIdx.x * 128 + wave * 32;

  // Q as B operand: lane holds Q[q=l16][d = quad*8+j], two q-sets x two halves
  bf16x8 qf[2][2];
#pragma unroll
  for (int qs = 0; qs < 2; qs++) {
    qf[qs][0] = ld_frag(Q + (qbase + qs * 16 + l16) * 64 + quad * 8);
    qf[qs][1] = ld_frag(Q + (qbase + qs * 16 + l16) * 64 + 32 + quad * 8);
  }

  f32x4 o[2][4] = {};              // O^T[d = nt*16+quad*4+r][q = l16] per set
  float m[2] = {-1e30f, -1e30f}, l[2] = {0.f, 0.f};

  // staging: issue i covers 8 rows (128B each): r = wave*16 + i*8 + lane/8
  const int srow = lane >> 3;                // 0..7
  const int sx = (lane & 7) ^ srow;          // swizzled source seg (16B units)
  const int kr0 = wave * 16 + srow;
  const int kr1 = wave * 16 + 8 + srow;

  // K fragment seg offsets (u16 units): (g ^ (l16&7))*8
  const int fs0 = ((0 * 4 + quad) ^ (l16 & 7)) * 8;
  const int fs1 = ((1 * 4 + quad) ^ (l16 & 7)) * 8;
  // V fragment segs: permuted so P's register layout matches (bitrev2)
  const int sV = ((quad & 1) << 1) | (quad >> 1);
  const int fv0 = ((0 * 4 + sV) ^ (l16 & 7)) * 8;
  const int fv1 = ((1 * 4 + sV) ^ (l16 & 7)) * 8;

  auto stage = [&](int buf, int j0) {
    gload16(Kp + (long)(j0 + kr0) * 64 + sx * 8, &Ks[buf][(wave * 2 + 0) * 512]);
    gload16(Kp + (long)(j0 + kr1) * 64 + sx * 8, &Ks[buf][(wave * 2 + 1) * 512]);
    gload16(Vt + (long)kr0 * 2048 + j0 + sx * 8, &Vs[buf][(wave * 2 + 0) * 512]);
    gload16(Vt + (long)kr1 * 2048 + j0 + sx * 8, &Vs[buf][(wave * 2 + 1) * 512]);
  };

  stage(0, jbeg);

#pragma unroll 1
  for (int j0 = jbeg; j0 < jend; j0 += 64) {
    const int buf = (j0 >> 6) & 1;
    __syncthreads();                       // staged chunk visible; prev body done
    if (j0 + 64 < jend) stage(buf ^ 1, j0 + 64);

    // ---- S^T = K Q^T over 64 keys, both q-sets (K frags shared) ----
    const u16* kb = &Ks[buf][0];
    f32x4 st[2][4];
#pragma unroll
    for (int f = 0; f < 4; f++) {
      bf16x8 k0 = ld_frag(kb + (f * 16 + l16) * 64 + fs0);
      bf16x8 k1 = ld_frag(kb + (f * 16 + l16) * 64 + fs1);
      f32x4 s0 = {}, s1 = {};
      s0 = MFMA16(k0, qf[0][0], s0); s0 = MFMA16(k1, qf[0][1], s0);
      s1 = MFMA16(k0, qf[1][0], s1); s1 = MFMA16(k1, qf[1][1], s1);
      st[0][f] = s0; st[1][f] = s1;
    }

    // ---- V frags (shared across q-sets), permuted segments ----
    const u16* vb = &Vs[buf][0];
    bf16x8 vf[4][2];
#pragma unroll
    for (int nt = 0; nt < 4; nt++) {
      vf[nt][0] = ld_frag(vb + (nt * 16 + l16) * 64 + fv0);
      vf[nt][1] = ld_frag(vb + (nt * 16 + l16) * 64 + fv1);
    }

    // ---- per q-set: online softmax (defer-max) + in-register P + PV ----
#pragma unroll
    for (int qs = 0; qs < 2; qs++) {
      float mx = -1e30f;
#pragma unroll
      for (int f = 0; f < 4; f++)
        mx = fmaxf(mx, fmaxf(fmaxf(st[qs][f][0], st[qs][f][1]),
                             fmaxf(st[qs][f][2], st[qs][f][3])));
      mx = fmaxf(mx, __shfl_xor(mx, 16));
      mx = fmaxf(mx, __shfl_xor(mx, 32));
      if (__any(mx > m[qs] + 8.0f)) {      // T13: skip rescale for small growth
        float mn = fmaxf(m[qs], mx);
        float al = fexp2(m[qs] - mn);
        m[qs] = mn;
        l[qs] *= al;
#pragma unroll
        for (int nt = 0; nt < 4; nt++) {
          o[qs][nt][0] *= al; o[qs][nt][1] *= al;
          o[qs][nt][2] *= al; o[qs][nt][3] *= al;
        }
      }
      float sm = 0.f;
      u32 wp[4][2];
#pragma unroll
      for (int f = 0; f < 4; f++) {
        float p0 = fexp2(st[qs][f][0] - m[qs]);
        float p1 = fexp2(st[qs][f][1] - m[qs]);
        float p2 = fexp2(st[qs][f][2] - m[qs]);
        float p3 = fexp2(st[qs][f][3] - m[qs]);
        sm += (p0 + p1) + (p2 + p3);
        wp[f][0] = packtrunc(p0, p1);
        wp[f][1] = packtrunc(p2, p3);
      }
      sm += __shfl_xor(sm, 16);
      sm += __shfl_xor(sm, 32);
      l[qs] += sm;

      // redistribute P words across quad pairs; even quads keep f-low pair
#pragma unroll
      for (int kh = 0; kh < 2; kh++) {
        const int flo = kh * 2, fhi = flo + 1;
        u32 tx0 = (quad & 1) ? wp[flo][0] : wp[fhi][0];
        u32 tx1 = (quad & 1) ? wp[flo][1] : wp[fhi][1];
        u32 rx0 = __shfl_xor(tx0, 16);
        u32 rx1 = __shfl_xor(tx1, 16);
        uint4 fw;
        fw.x = (quad & 1) ? rx0 : wp[flo][0];
        fw.y = (quad & 1) ? rx1 : wp[flo][1];
        fw.z = (quad & 1) ? wp[fhi][0] : rx0;
        fw.w = (quad & 1) ? wp[fhi][1] : rx1;
        bf16x8 pf = __builtin_bit_cast(bf16x8, fw);
#pragma unroll
        for (int nt = 0; nt < 4; nt++)
          o[qs][nt] = MFMA16(vf[nt][kh], pf, o[qs][nt]);
      }
    }
  }

  // ---- epilogue: write unnormalized partial O (fp32) + (m,l) per q-row ----
  float* oDst = kz ? oP1 : oP0;
  float* mlDst = kz ? ml1 : ml0;
#pragma unroll
  for (int qs = 0; qs < 2; qs++) {
    const long row = (long)bh * 2048 + qbase + qs * 16 + l16;
#pragma unroll
    for (int nt = 0; nt < 4; nt++)
      *(float4*)(oDst + row * 64 + nt * 16 + quad * 4) =
          *(const float4*)&o[qs][nt];
    if (quad == 0) {
      float2 ml2 = {m[qs], l[qs]};
      *(float2*)(mlDst + row * 2) = ml2;
    }
  }
}

// ---------------- merge the two key-halves -> ctx bf16 ----------------------
__global__ __launch_bounds__(256) void attn_combine_k(
    const float* __restrict__ o0, const float* __restrict__ o1,
    const float* __restrict__ ml0, const float* __restrict__ ml1,
    u16* __restrict__ ctx) {
  long i = ((long)blockIdx.x * 256 + threadIdx.x) * 4;  // element index
  long row = i >> 6;             // bh*2048 + ll
  int d = (int)(i & 63);
  float2 a0 = *(const float2*)(ml0 + row * 2);
  float2 a1 = *(const float2*)(ml1 + row * 2);
  float M = fmaxf(a0.x, a1.x);
  float w0 = fexp2(a0.x - M), w1 = fexp2(a1.x - M);
  float rinv = 1.0f / (a0.y * w0 + a1.y * w1);
  float4 v0 = *(const float4*)(o0 + i);
  float4 v1 = *(const float4*)(o1 + i);
  int bh = (int)(row >> 11), ll = (int)(row & 2047);
  int bI = bh >> 4, hh = bh & 15;
  ushort4 w;
  w.x = f2bf((v0.x * w0 + v1.x * w1) * rinv);
  w.y = f2bf((v0.y * w0 + v1.y * w1) * rinv);
  w.z = f2bf((v0.z * w0 + v1.z * w1) * rinv);
  w.w = f2bf((v0.w * w0 + v1.w * w1) * rinv);
  *(ushort4*)(ctx + ((long)(bI * 2048 + ll) * 1024) + hh * 64 + d) = w;
}

// ---- residual + 4-slab split-K reduce + bias + LayerNorm ------------------
// outF fp32 always; outB bf16 optional. Slabs may alias outF region:
// all reads of a row precede all writes (block == row, barrier between).
__global__ __launch_bounds__(256) void ln4b_k(const float* __restrict__ a,
                                              const float* __restrict__ q0,
                                              const float* __restrict__ q1,
                                              const float* __restrict__ q2,
                                              const float* __restrict__ q3,
                                              const float* __restrict__ bias,
                                              const float* __restrict__ g,
                                              const float* __restrict__ be,
                                              float* __restrict__ outF,
                                              u16* __restrict__ outB) {
  const int row = blockIdx.x, tid = threadIdx.x;
  const long base = (long)row * 1024;
  float v[4], s = 0.f, sq = 0.f;
#pragma unroll
  for (int i = 0; i < 4; i++) {
    int c = i * 256 + tid;
    float ff = (q0[base + c] + q1[base + c]) + (q2[base + c] + q3[base + c]) + bias[c];
    v[i] = a[base + c] + ff;
    s += v[i];
    sq += v[i] * v[i];
  }
#pragma unroll
  for (int off = 1; off < 64; off <<= 1) {
    s += __shfl_xor(s, off);
    sq += __shfl_xor(sq, off);
  }
  __shared__ float red[10];
  int wave = tid >> 6, lane = tid & 63;
  if (lane == 0) { red[wave * 2] = s; red[wave * 2 + 1] = sq; }
  __syncthreads();
  if (tid == 0) {
    float S = red[0] + red[2] + red[4] + red[6];
    float Q = red[1] + red[3] + red[5] + red[7];
    float mu = S * (1.0f / 1024.0f);
    float var = Q * (1.0f / 1024.0f) - mu * mu;
    red[8] = mu;
    red[9] = rsqrtf(var + 1e-5f);
  }
  __syncthreads();
  float mu = red[8], rstd = red[9];
#pragma unroll
  for (int i = 0; i < 4; i++) {
    int c = i * 256 + tid;
    float o = (v[i] - mu) * rstd * g[c] + be[c];
    outF[base + c] = o;
    if (outB) outB[base + c] = f2bf(o);
  }
}

// ---------------------------------------------------------------------------
extern "C" void kernel_launch(void* const* d_in, const int* in_sizes, int n_in,
                              void* d_out, int out_size, void* d_ws, size_t ws_size,
                              hipStream_t stream) {
  const float* x  = (const float*)d_in[0];
  const float* Wq = (const float*)d_in[1];  const float* bq = (const float*)d_in[2];
  const float* Wk = (const float*)d_in[3];  const float* bk = (const float*)d_in[4];
  const float* Wv = (const float*)d_in[5];  const float* bv = (const float*)d_in[6];
  const float* Wo = (const float*)d_in[7];  const float* bo = (const float*)d_in[8];
  const float* W1 = (const float*)d_in[9];  const float* b1 = (const float*)d_in[10];
  const float* W2 = (const float*)d_in[11]; const float* b2 = (const float*)d_in[12];
  const float* g1 = (const float*)d_in[13]; const float* be1 = (const float*)d_in[14];
  const float* g2 = (const float*)d_in[15]; const float* be2 = (const float*)d_in[16];

  char* ws = (char*)d_ws;
  size_t off = 0;
  auto alloc = [&](size_t bytes) {
    size_t o = off;
    off += (bytes + 255) & ~(size_t)255;
    return o;
  };
  u16*   xb     = (u16*)(ws + alloc(4096UL * 1024 * 2));
  u16*   wqkvT  = (u16*)(ws + alloc(3072UL * 1024 * 2));
  u16*   woT    = (u16*)(ws + alloc(1024UL * 1024 * 2));
  u16*   w1T    = (u16*)(ws + alloc(4096UL * 1024 * 2));
  u16*   w2T    = (u16*)(ws + alloc(1024UL * 4096 * 2));
  u16*   qb     = (u16*)(ws + alloc(32UL * 2048 * 64 * 2));   // 8 MiB
  u16*   kb     = (u16*)(ws + alloc(32UL * 2048 * 64 * 2));   // 8 MiB (contig after qb)
  u16*   vTb    = (u16*)(ws + alloc(32UL * 64 * 2048 * 2));   // 8 MiB (contig)
  u16*   ctx    = (u16*)(ws + alloc(4096UL * 1024 * 2));      // 8 MiB (contig after vTb)
  float* attnO  = (float*)(ws + alloc(4096UL * 1024 * 4));    // 16 MiB
  float* h      = (float*)(ws + alloc(4096UL * 1024 * 4));    // 16 MiB
  u16*   hb     = (u16*)(ws + alloc(4096UL * 1024 * 2));      // 8 MiB
  u16*   ff1    = (u16*)(ws + alloc(4096UL * 4096 * 2));      // 32 MiB
  float* ff2    = (float*)(ws + alloc(4096UL * 1024 * 4));    // 16 MiB
  if (off > ws_size) return;  // workspace too small: bail (bench will flag)

  // attention partials (alias regions dead during steps 3/3.5):
  float* oPart0 = attnO;
  float* oPart1 = h;
  float* mlP0   = (float*)hb;
  float* mlP1   = (float*)hb + 32 * 2048 * 2;

  // Wo split-K=4 slabs (dead regions during step 4; consumed by LN1):
  float* wl0 = attnO;               // combine output done with oPart0
  float* wl1 = ff2;
  float* wl2 = (float*)ff1;         // ff1 = 32 MiB -> two 16 MiB slabs
  float* wl3 = (float*)ff1 + 4UL * 1024 * 1024;

  // FFN-down split-K=4 slabs (dead regions during step 7):
  float* sl0 = ff2;
  float* sl1 = attnO;
  float* sl2 = (float*)qb;    // covers qb+kb (16 MiB contiguous)
  float* sl3 = (float*)vTb;   // covers vTb+ctx (16 MiB contiguous)

  // 1) bf16 conversions / weight transposes
  cvt_bf16_k<<<4096, 256, 0, stream>>>(x, xb);
  transpose4_bf16_k<<<dim3(32, 32, 4), 256, 0, stream>>>(Wq, Wk, Wv, Wo, wqkvT, woT);
  transpose_bf16_k<<<dim3(128, 32), 256, 0, stream>>>(W1, w1T, 1024, 4096);
  transpose_bf16_k<<<dim3(32, 128), 256, 0, stream>>>(W2, w2T, 4096, 1024);

  // 2) QKV projection (N=3072 fused), scatter epilogue — 256^2 pipelined
  gemm256_k<0><<<dim3(12, 16), 512, 0, stream>>>(
      xb, wqkvT, 3072, 1024, 1024, 1024,
      nullptr, nullptr, nullptr, nullptr, nullptr, nullptr,
      qb, kb, vTb, bq, bk, bv);
  // 3) attention: key-split 2 -> 1024 blocks, partial O + (m,l)
  attn_k<<<dim3(16, 32, 2), 256, 0, stream>>>(qb, kb, vTb,
                                              oPart0, oPart1, mlP0, mlP1);
  // 3.5) merge halves -> ctx (bf16)
  attn_combine_k<<<4096, 256, 0, stream>>>(oPart0, oPart1, mlP0, mlP1, ctx);
  // 4) output projection: 256^2 pipelined, split-K=4 partial slabs
  gemm256_k<3><<<dim3(4, 16, 4), 512, 0, stream>>>(
      ctx, woT, 1024, 1024, 1024, 256,
      nullptr, wl0, nullptr, wl1, wl2, wl3,
      nullptr, nullptr, nullptr, nullptr, nullptr, nullptr);
  // 5) residual + slab-reduce + bo + LN1 (fp32 h + bf16 hb)
  ln4b_k<<<4096, 256, 0, stream>>>(x, wl0, wl1, wl2, wl3, bo, g1, be1, h, hb);
  // 6) FFN up + GELU — 256^2 pipelined
  gemm256_k<2><<<dim3(16, 16), 512, 0, stream>>>(
      hb, w1T, 4096, 1024, 1024, 1024,
      b1, nullptr, ff1, nullptr, nullptr, nullptr,
      nullptr, nullptr, nullptr, nullptr, nullptr, nullptr);
  // 7) FFN down — 256^2 pipelined, split-K=4 partial slabs
  gemm256_k<3><<<dim3(4, 16, 4), 512, 0, stream>>>(
      ff1, w2T, 1024, 4096, 4096, 1024,
      nullptr, sl0, nullptr, sl1, sl2, sl3,
      nullptr, nullptr, nullptr, nullptr, nullptr, nullptr);
  // 8) residual + slab-reduce + b2 + LN2 -> out
  ln4b_k<<<4096, 256, 0, stream>>>(h, sl0, sl1, sl2, sl3, b2, g2, be2,
                                   (float*)d_out, nullptr);
}

// Round 4
// 400.560 us; speedup vs baseline: 1.0487x; 1.0487x over previous
//
#include <hip/hip_runtime.h>
#include <cmath>

// ---------------------------------------------------------------------------
// EncoderLayer: x -> MHA -> +res -> LN1 -> FFN(GELU) -> +res -> LN2
// B=2 L=2048 D=1024 H=16 dk=64 F=4096  (M = B*L = 4096 rows)
// bf16 MFMA 16x16x32, fp32 accumulate, fp32 LN/residual.
//
// Round 4 changes:
//  * attn: keep in-register P (round-3 math, proven correct) but fix the
//    register budget: __launch_bounds__(256,3) (170 total regs; round 3's
//    (256,4) forced 64 arch VGPRs alongside 64 unified-file accs -> scratch
//    spills, +31 MB HBM traffic).
//  * QKV: new 128x128-tile 4-wave kernel (grid 768 = 3 blocks/CU; gemm256
//    gave only 192 blocks = 0.75/CU, 64 CUs idle). Ring-3 LDS, counted
//    vmcnt(4), ONE barrier per K-tile (no drain).
//  * Wo/LN1: reverted to round-2 legacy gemm_k<1,64> + ln_k (split-K Wo
//    cost +6us in LN1 slab reads).
// ---------------------------------------------------------------------------

typedef unsigned short u16;
typedef unsigned int u32;
typedef __attribute__((ext_vector_type(8))) __bf16 bf16x8;
typedef __attribute__((ext_vector_type(4))) float f32x4;

#define MFMA16(a, b, c) __builtin_amdgcn_mfma_f32_16x16x32_bf16(a, b, c, 0, 0, 0)

__device__ __forceinline__ u16 f2bf(float f) {
  u32 u = __builtin_bit_cast(u32, f);
  u += 0x7fffu + ((u >> 16) & 1u);   // round-to-nearest-even
  return (u16)(u >> 16);
}

// truncation-pack two fp32 -> bf16x2 in ONE v_perm_b32
__device__ __forceinline__ u32 packtrunc(float lo, float hi) {
#if __has_builtin(__builtin_amdgcn_perm)
  return __builtin_amdgcn_perm(__builtin_bit_cast(u32, hi),
                               __builtin_bit_cast(u32, lo), 0x07060302u);
#else
  return (__builtin_bit_cast(u32, lo) >> 16) |
         (__builtin_bit_cast(u32, hi) & 0xFFFF0000u);
#endif
}

__device__ __forceinline__ bf16x8 ld_frag(const u16* p) {
  return __builtin_bit_cast(bf16x8, *(const uint4*)p);
}

__device__ __forceinline__ float fexp2(float x) {
#if __has_builtin(__builtin_amdgcn_exp2f)
  return __builtin_amdgcn_exp2f(x);
#else
  return exp2f(x);
#endif
}

// async global->LDS, 16B per lane; LDS dest = wave-uniform base + lane*16
__device__ __forceinline__ void gload16(const u16* g, u16* l) {
  __builtin_amdgcn_global_load_lds(
      (const __attribute__((address_space(1))) void*)g,
      (__attribute__((address_space(3))) void*)l, 16, 0, 0);
}

// counted waits: gate vmem retirement without draining the pipeline, and
// drain own LDS reads before buffer-recycling barriers.
#define WAITVL(N) asm volatile("s_waitcnt vmcnt(" #N ") lgkmcnt(0)" ::: "memory")
#define BAR() do { __builtin_amdgcn_s_barrier(); asm volatile("" ::: "memory"); } while (0)

// ---------------- fp32 -> bf16 elementwise convert (x) ----------------------
__global__ __launch_bounds__(256) void cvt_bf16_k(const float* __restrict__ src,
                                                  u16* __restrict__ dst) {
  int i = (blockIdx.x * 256 + threadIdx.x) * 4;
  float4 v = *(const float4*)(src + i);
  ushort4 o;
  o.x = f2bf(v.x); o.y = f2bf(v.y); o.z = f2bf(v.z); o.w = f2bf(v.w);
  *(ushort4*)(dst + i) = o;
}

// ---------------- fp32 [R][C] -> bf16 [C][R] transpose ----------------------
__global__ __launch_bounds__(256) void transpose_bf16_k(const float* __restrict__ src,
                                                        u16* __restrict__ dst,
                                                        int R, int C) {
  __shared__ float tile[32][33];
  int tx = threadIdx.x & 31, ty = threadIdx.x >> 5;  // 32 x 8
  int c0 = blockIdx.x * 32, r0 = blockIdx.y * 32;
#pragma unroll
  for (int i = 0; i < 4; i++)
    tile[ty + 8 * i][tx] = src[(long)(r0 + ty + 8 * i) * C + c0 + tx];
  __syncthreads();
#pragma unroll
  for (int i = 0; i < 4; i++)
    dst[(long)(c0 + ty + 8 * i) * R + r0 + tx] = f2bf(tile[tx][ty + 8 * i]);
}

// ---- 4x 1024x1024 fp32 -> bf16 transposes in one launch (z picks matrix) ---
__global__ __launch_bounds__(256) void transpose4_bf16_k(
    const float* __restrict__ Wq, const float* __restrict__ Wk,
    const float* __restrict__ Wv, const float* __restrict__ Wo,
    u16* __restrict__ wqkvT, u16* __restrict__ woT) {
  const int z = blockIdx.z;
  const float* src = (z == 0) ? Wq : (z == 1) ? Wk : (z == 2) ? Wv : Wo;
  u16* dst = (z < 3) ? (wqkvT + (size_t)z * 1024 * 1024) : woT;
  __shared__ float tile[32][33];
  int tx = threadIdx.x & 31, ty = threadIdx.x >> 5;
  int c0 = blockIdx.x * 32, r0 = blockIdx.y * 32;
#pragma unroll
  for (int i = 0; i < 4; i++)
    tile[ty + 8 * i][tx] = src[(long)(r0 + ty + 8 * i) * 1024 + c0 + tx];
  __syncthreads();
#pragma unroll
  for (int i = 0; i < 4; i++)
    dst[(long)(c0 + ty + 8 * i) * 1024 + r0 + tx] = f2bf(tile[tx][ty + 8 * i]);
}

// ---------------------------------------------------------------------------
// gemm128_qkv: C = A[4096][1024] * wqkvT[3072][1024]^T, scattered to q/k/vT.
// 128x128 tile, BK=32, 4 waves (2x2), per-wave 64x64 (4x4 frags).
// LDS ring-3 (A+B 16 KiB/tile = 48 KiB) -> 3 blocks/CU with (256,3).
// stage(t+2) issued during tile t; gate = WAITVL(4) (own stage(t) retired;
// stage(t+1) stays in flight) + BAR. Single barrier per K-tile, no drain.
// Buffer (t+2)%3 == (t-1)%3 is safe: readers of t-1 drained lgkm before BAR.
// ---------------------------------------------------------------------------
__global__ __launch_bounds__(256, 3) void gemm128_qkv_k(
    const u16* __restrict__ A, const u16* __restrict__ BT,
    u16* __restrict__ qd, u16* __restrict__ kd, u16* __restrict__ vTd,
    const float* __restrict__ bq, const float* __restrict__ bk,
    const float* __restrict__ bv) {
  constexpr int K = 1024, KT = 32;
  __shared__ u16 As[3][128 * 32];   // 24 KiB
  __shared__ u16 Bs[3][128 * 32];   // 24 KiB
  const int tid = threadIdx.x;
  const int wave = tid >> 6, lane = tid & 63, quad = lane >> 4, l16 = lane & 15;
  const int wm = wave >> 1, wn = wave & 1;
  const int m0 = blockIdx.y * 128, n0 = blockIdx.x * 128;

  // staging: per wave 2 A-issues + 2 B-issues (16 rows x 64B each);
  // global source seg pre-XORed so linear LDS + XOR read line up.
  const int srow = lane >> 2;
  const int sseg = (lane & 3) ^ (srow & 3);
  const u16* aS = A + (long)(m0 + wave * 32 + srow) * K + sseg * 8;
  const u16* bS = BT + (long)(n0 + wave * 32 + srow) * K + sseg * 8;

  auto stage = [&](int sb, int s) {
    const u16* pa = aS + s * 32;
    gload16(pa, &As[sb][wave * 1024]);
    gload16(pa + 16 * K, &As[sb][wave * 1024 + 512]);
    const u16* pb = bS + s * 32;
    gload16(pb, &Bs[sb][wave * 1024]);
    gload16(pb + 16 * K, &Bs[sb][wave * 1024 + 512]);
  };

  int aro[4], bro[4];
#pragma unroll
  for (int f = 0; f < 4; f++) {
    int ra = wm * 64 + f * 16 + l16;
    aro[f] = ra * 32 + ((quad ^ (ra & 3)) * 8);
    int rb = wn * 64 + f * 16 + l16;
    bro[f] = rb * 32 + ((quad ^ (rb & 3)) * 8);
  }

  f32x4 acc[4][4] = {};

  stage(0, 0);
  stage(1, 1);
  int buf = 0;
#pragma unroll 1
  for (int t = 0; t < KT; ++t) {
    if (t < KT - 1) { WAITVL(4); } else { WAITVL(0); }
    BAR();
    bf16x8 af[4], bfr[4];
#pragma unroll
    for (int i = 0; i < 4; i++) af[i] = ld_frag(&As[buf][aro[i]]);
#pragma unroll
    for (int i = 0; i < 4; i++) bfr[i] = ld_frag(&Bs[buf][bro[i]]);
    if (t + 2 < KT) {
      int nb = buf + 2; if (nb >= 3) nb -= 3;
      stage(nb, t + 2);
    }
    __builtin_amdgcn_s_setprio(1);
#pragma unroll
    for (int mf = 0; mf < 4; mf++)
#pragma unroll
      for (int nf = 0; nf < 4; nf++)
        acc[mf][nf] = MFMA16(af[mf], bfr[nf], acc[mf][nf]);
    __builtin_amdgcn_s_setprio(0);
    if (++buf == 3) buf = 0;
  }

  // scatter epilogue (q: folded exp2 scale; k: plain; v: transposed)
  const int nbase = n0 + wn * 64;            // wave-uniform
  const int mat = nbase >> 10;               // 0=q 1=k 2=v (64-col range never crosses)
  const float* bp = (mat == 0) ? bq : ((mat == 1) ? bk : bv);
  float bb[4];
  int hh0[4], dd0[4];
#pragma unroll
  for (int nf = 0; nf < 4; nf++) {
    int nn = (nbase + nf * 16 + l16) & 1023;
    bb[nf] = bp[nn];
    hh0[nf] = nn >> 6;
    dd0[nf] = nn & 63;
  }
  if (mat < 2) {
#pragma unroll
    for (int mf = 0; mf < 4; mf++) {
#pragma unroll
      for (int r = 0; r < 4; r++) {
        int mr = m0 + wm * 64 + mf * 16 + quad * 4 + r;
        int bI = mr >> 11, ll = mr & 2047;
#pragma unroll
        for (int nf = 0; nf < 4; nf++) {
          float v = acc[mf][nf][r] + bb[nf];
          long idx = ((long)((bI * 16 + hh0[nf]) * 2048 + ll)) * 64 + dd0[nf];
          if (mat == 0) {
            qd[idx] = f2bf(v * 0.18033688011112043f);  // 1/sqrt(dk)*log2(e)
          } else {
            kd[idx] = f2bf(v);
          }
        }
      }
    }
  } else {
#pragma unroll
    for (int nf = 0; nf < 4; nf++) {
#pragma unroll
      for (int mf = 0; mf < 4; mf++) {
#pragma unroll
        for (int r = 0; r < 4; r++) {
          int mr = m0 + wm * 64 + mf * 16 + quad * 4 + r;
          int bI = mr >> 11, ll = mr & 2047;
          float v = acc[mf][nf][r] + bb[nf];
          vTd[((long)((bI * 16 + hh0[nf]) * 64 + dd0[nf])) * 2048 + ll] = f2bf(v);
        }
      }
    }
  }
}

// ---------------------------------------------------------------------------
// gemm256: C[M][N] = A[M][K] * BT[N][K]^T, 256x256 block tile, BK=32,
// 8 waves (2 wm x 4 wn), per-wave 128x64 output (8 m-frags x 4 n-frags).
// LDS: 4-deep ring of (A 256x32 + B 256x32) bf16 = 128 KiB. Counted
// vmcnt(8) gate; 2 barrier-sandwiched phases of 16 MFMA per K-tile.
// MODE 2: GELU->bf16; MODE 3: fp32 partial slab (kz).
// ---------------------------------------------------------------------------
template <int MODE>
__global__ __launch_bounds__(512, 2) void gemm256_k(
    const u16* __restrict__ A, const u16* __restrict__ BT,
    int N, int lda, int ldb, int Kc,
    const float* __restrict__ bias, float* __restrict__ outF, u16* __restrict__ outB,
    float* __restrict__ p1, float* __restrict__ p2, float* __restrict__ p3) {
  __shared__ u16 As[4][256 * 32];   // 64 KiB
  __shared__ u16 Bs[4][256 * 32];   // 64 KiB
  const int tid = threadIdx.x;
  const int wave = tid >> 6, lane = tid & 63, quad = lane >> 4, l16 = lane & 15;
  const int wm = wave >> 2, wn = wave & 3;
  const int m0 = blockIdx.y * 256, n0 = blockIdx.x * 256;
  const int kz = blockIdx.z;
  const long kofs = (long)kz * Kc;
  const int KT = Kc >> 5;

  const int srow = lane >> 2;
  const int sseg = (lane & 3) ^ (srow & 3);
  const u16* aS = A + (long)(m0 + wave * 32 + srow) * lda + kofs + sseg * 8;
  const u16* bS = BT + (long)(n0 + wave * 32 + srow) * ldb + kofs + sseg * 8;

  auto stageA = [&](int sb, int s) {
    const u16* p = aS + (long)s * 32;
    gload16(p, &As[sb][wave * 1024]);
    gload16(p + 16 * (long)lda, &As[sb][wave * 1024 + 512]);
  };
  auto stageB = [&](int sb, int s) {
    const u16* p = bS + (long)s * 32;
    gload16(p, &Bs[sb][wave * 1024]);
    gload16(p + 16 * (long)ldb, &Bs[sb][wave * 1024 + 512]);
  };

  int aro[8], bro[4];
#pragma unroll
  for (int mf = 0; mf < 8; mf++) {
    int r = wm * 128 + mf * 16 + l16;
    aro[mf] = r * 32 + ((quad ^ (r & 3)) * 8);
  }
#pragma unroll
  for (int nf = 0; nf < 4; nf++) {
    int r = wn * 64 + nf * 16 + l16;
    bro[nf] = r * 32 + ((quad ^ (r & 3)) * 8);
  }

  f32x4 acc[8][4] = {};

  stageA(0, 0); stageB(0, 0);
  stageA(1, 1); stageB(1, 1);
  stageA(2, 2); stageB(2, 2);

#pragma unroll 1
  for (int t = 0; t < KT; ++t) {
    const int buf = t & 3;
    if (t < KT - 2)      { WAITVL(8); }
    else if (t == KT - 2){ WAITVL(4); }
    else                 { WAITVL(0); }
    BAR();

    bf16x8 af[4], bf4[4];
#pragma unroll
    for (int i = 0; i < 4; i++) af[i] = ld_frag(&As[buf][aro[i]]);
#pragma unroll
    for (int i = 0; i < 4; i++) bf4[i] = ld_frag(&Bs[buf][bro[i]]);
    if (t + 3 < KT) stageA((t + 3) & 3, t + 3);
    BAR();
    __builtin_amdgcn_s_setprio(1);
#pragma unroll
    for (int mf = 0; mf < 4; mf++)
#pragma unroll
      for (int nf = 0; nf < 4; nf++)
        acc[mf][nf] = MFMA16(af[mf], bf4[nf], acc[mf][nf]);
    __builtin_amdgcn_s_setprio(0);

    bf16x8 ag[4];
#pragma unroll
    for (int i = 0; i < 4; i++) ag[i] = ld_frag(&As[buf][aro[4 + i]]);
    if (t + 3 < KT) stageB((t + 3) & 3, t + 3);
    BAR();
    __builtin_amdgcn_s_setprio(1);
#pragma unroll
    for (int mf = 0; mf < 4; mf++)
#pragma unroll
      for (int nf = 0; nf < 4; nf++)
        acc[4 + mf][nf] = MFMA16(ag[mf], bf4[nf], acc[4 + mf][nf]);
    __builtin_amdgcn_s_setprio(0);
  }

  if (MODE == 2) {
    float bb[4];
#pragma unroll
    for (int nf = 0; nf < 4; nf++) bb[nf] = bias[n0 + wn * 64 + nf * 16 + l16];
#pragma unroll
    for (int mf = 0; mf < 8; mf++) {
#pragma unroll
      for (int r = 0; r < 4; r++) {
        int mr = m0 + wm * 128 + mf * 16 + quad * 4 + r;
        u16* orow = outB + (long)mr * N + n0 + wn * 64 + l16;
#pragma unroll
        for (int nf = 0; nf < 4; nf++) {
          float v = acc[mf][nf][r] + bb[nf];
          v = 0.5f * v * (1.0f + erff(v * 0.70710678118654752f));  // exact GELU
          orow[nf * 16] = f2bf(v);
        }
      }
    }
  } else {  // MODE 3: fp32 partial slab per kz (bias folded into LN reduce)
    float* sl = (kz == 0) ? outF : (kz == 1) ? p1 : (kz == 2) ? p2 : p3;
#pragma unroll
    for (int mf = 0; mf < 8; mf++) {
#pragma unroll
      for (int r = 0; r < 4; r++) {
        int mr = m0 + wm * 128 + mf * 16 + quad * 4 + r;
        float* orow = sl + (long)mr * N + n0 + wn * 64 + l16;
#pragma unroll
        for (int nf = 0; nf < 4; nf++) orow[nf * 16] = acc[mf][nf][r];
      }
    }
  }
}

// ---------------- GEMM: C[M][N] = A[M][K] * BT[N][K]^T (legacy, Wo only) ----
template <int MODE, int TN>
__global__ __launch_bounds__(256) void gemm_k(
    const u16* __restrict__ A, const u16* __restrict__ BT, int M, int N, int K,
    const float* __restrict__ bias, float* __restrict__ outF) {
  constexpr int NT = TN / 32;           // n-tiles per wave (4 or 2)
  __shared__ u16 As[2][128 * 32];
  __shared__ u16 Bs[2][TN * 32];
  const int tid = threadIdx.x;
  const int wave = tid >> 6, lane = tid & 63, quad = lane >> 4, l16 = lane & 15;
  const int wm = wave >> 1, wn = wave & 1;
  const int m0 = blockIdx.y * 128, n0 = blockIdx.x * TN;

  const int srow = lane >> 2;                  // 0..15
  const int sxor = (lane & 3) ^ (srow & 3);    // swizzled source seg
  const u16* aS0 = A + (long)(m0 + wave * 32 + srow) * K + sxor * 8;
  const u16* aS1 = aS0 + 16 * K;
  const u16* bS0 = BT + (long)(n0 + (TN == 128 ? wave * 32 : wave * 16) + srow) * K + sxor * 8;
  const u16* bS1 = bS0 + 16 * K;  // used only when TN==128

  int aoff[4], boff[NT];
#pragma unroll
  for (int t = 0; t < 4; t++) {
    int ra = wm * 64 + t * 16 + l16;
    aoff[t] = ra * 32 + ((quad ^ (l16 & 3)) * 8);
  }
#pragma unroll
  for (int t = 0; t < NT; t++) {
    int rb = wn * (TN / 2) + t * 16 + l16;
    boff[t] = rb * 32 + ((quad ^ (l16 & 3)) * 8);
  }

  auto stage = [&](int buf, int k0) {
    gload16(aS0 + k0, &As[buf][(wave * 2 + 0) * 512]);
    gload16(aS1 + k0, &As[buf][(wave * 2 + 1) * 512]);
    if (TN == 128) {
      gload16(bS0 + k0, &Bs[buf][(wave * 2 + 0) * 512]);
      gload16(bS1 + k0, &Bs[buf][(wave * 2 + 1) * 512]);
    } else {
      gload16(bS0 + k0, &Bs[buf][wave * 512]);
    }
  };

  f32x4 acc[4][NT] = {};

  stage(0, 0);
#pragma unroll 1
  for (int k0 = 0; k0 < K; k0 += 32) {
    const int buf = (k0 >> 5) & 1;
    __syncthreads();
    if (k0 + 32 < K) stage(buf ^ 1, k0 + 32);
    bf16x8 af[4], bfr[NT];
#pragma unroll
    for (int t = 0; t < 4; t++) af[t] = ld_frag(&As[buf][aoff[t]]);
#pragma unroll
    for (int t = 0; t < NT; t++) bfr[t] = ld_frag(&Bs[buf][boff[t]]);
#pragma unroll
    for (int mt = 0; mt < 4; mt++)
#pragma unroll
      for (int nt = 0; nt < NT; nt++)
        acc[mt][nt] = MFMA16(af[mt], bfr[nt], acc[mt][nt]);
  }

  if (MODE == 1) {
    float bb[NT];
#pragma unroll
    for (int nt = 0; nt < NT; nt++) bb[nt] = bias[n0 + wn * (TN / 2) + nt * 16 + l16];
#pragma unroll
    for (int mt = 0; mt < 4; mt++) {
#pragma unroll
      for (int r = 0; r < 4; r++) {
        int mr = m0 + wm * 64 + mt * 16 + quad * 4 + r;
        float* orow = outF + (long)mr * N + n0 + wn * (TN / 2) + l16;
#pragma unroll
        for (int nt = 0; nt < NT; nt++)
          orow[nt * 16] = acc[mt][nt][r] + bb[nt];
      }
    }
  }
}

// ---------------- flash attention (S^T, LDS-staged K/V, key-split 2) --------
// grid (L/128, B*H, 2), 4 waves; wave owns 32 q rows (two 16-q sets); 64-key
// chunks over this block's 1024-key half. P^T kept in registers (one
// shfl_xor(16) pair per kh; V segs permuted by sV=bitrev2(quad)).
// (256,3): 170-reg budget fits 64 unified accs + ~100 arch, no spill.
__global__ __launch_bounds__(256, 3) void attn_k(const u16* __restrict__ qd,
                                                 const u16* __restrict__ kd,
                                                 const u16* __restrict__ vTd,
                                                 float* __restrict__ oP0,
                                                 float* __restrict__ oP1,
                                                 float* __restrict__ ml0,
                                                 float* __restrict__ ml1) {
  __shared__ u16 Ks[2][64 * 64];
  __shared__ u16 Vs[2][64 * 64];
  const int tid = threadIdx.x;
  const int wave = tid >> 6, lane = tid & 63, quad = lane >> 4, l16 = lane & 15;
  const int bh = blockIdx.y;
  const int kz = blockIdx.z;
  const int jbeg = kz * 1024, jend = jbeg + 1024;
  const u16* Q = qd + (long)bh * 2048 * 64;
  const u16* Kp = kd + (long)bh * 2048 * 64;
  const u16* Vt = vTd + (long)bh * 64 * 2048;
  const int qbase = blockIdx.x * 128 + wave * 32;

  bf16x8 qf[2][2];
#pragma unroll
  for (int qs = 0; qs < 2; qs++) {
    qf[qs][0] = ld_frag(Q + (qbase + qs * 16 + l16) * 64 + quad * 8);
    qf[qs][1] = ld_frag(Q + (qbase + qs * 16 + l16) * 64 + 32 + quad * 8);
  }

  f32x4 o[2][4] = {};
  float m[2] = {-1e30f, -1e30f}, l[2] = {0.f, 0.f};

  const int srow = lane >> 3;                // 0..7
  const int sx = (lane & 7) ^ srow;          // swizzled source seg (16B units)
  const int kr0 = wave * 16 + srow;
  const int kr1 = wave * 16 + 8 + srow;

  const int fs0 = ((0 * 4 + quad) ^ (l16 & 7)) * 8;
  const int fs1 = ((1 * 4 + quad) ^ (l16 & 7)) * 8;
  const int sV = ((quad & 1) << 1) | (quad >> 1);
  const int fv0 = ((0 * 4 + sV) ^ (l16 & 7)) * 8;
  const int fv1 = ((1 * 4 + sV) ^ (l16 & 7)) * 8;

  auto stage = [&](int buf, int j0) {
    gload16(Kp + (long)(j0 + kr0) * 64 + sx * 8, &Ks[buf][(wave * 2 + 0) * 512]);
    gload16(Kp + (long)(j0 + kr1) * 64 + sx * 8, &Ks[buf][(wave * 2 + 1) * 512]);
    gload16(Vt + (long)kr0 * 2048 + j0 + sx * 8, &Vs[buf][(wave * 2 + 0) * 512]);
    gload16(Vt + (long)kr1 * 2048 + j0 + sx * 8, &Vs[buf][(wave * 2 + 1) * 512]);
  };

  stage(0, jbeg);

#pragma unroll 1
  for (int j0 = jbeg; j0 < jend; j0 += 64) {
    const int buf = (j0 >> 6) & 1;
    __syncthreads();                       // staged chunk visible; prev body done
    if (j0 + 64 < jend) stage(buf ^ 1, j0 + 64);

    // ---- S^T = K Q^T over 64 keys, both q-sets (K frags shared) ----
    const u16* kb = &Ks[buf][0];
    f32x4 st[2][4];
#pragma unroll
    for (int f = 0; f < 4; f++) {
      bf16x8 k0 = ld_frag(kb + (f * 16 + l16) * 64 + fs0);
      bf16x8 k1 = ld_frag(kb + (f * 16 + l16) * 64 + fs1);
      f32x4 s0 = {}, s1 = {};
      s0 = MFMA16(k0, qf[0][0], s0); s0 = MFMA16(k1, qf[0][1], s0);
      s1 = MFMA16(k0, qf[1][0], s1); s1 = MFMA16(k1, qf[1][1], s1);
      st[0][f] = s0; st[1][f] = s1;
    }

    // ---- V frags (shared across q-sets), permuted segments ----
    const u16* vb = &Vs[buf][0];
    bf16x8 vf[4][2];
#pragma unroll
    for (int nt = 0; nt < 4; nt++) {
      vf[nt][0] = ld_frag(vb + (nt * 16 + l16) * 64 + fv0);
      vf[nt][1] = ld_frag(vb + (nt * 16 + l16) * 64 + fv1);
    }

    // ---- per q-set: online softmax (defer-max) + in-register P + PV ----
#pragma unroll
    for (int qs = 0; qs < 2; qs++) {
      float mx = -1e30f;
#pragma unroll
      for (int f = 0; f < 4; f++)
        mx = fmaxf(mx, fmaxf(fmaxf(st[qs][f][0], st[qs][f][1]),
                             fmaxf(st[qs][f][2], st[qs][f][3])));
      mx = fmaxf(mx, __shfl_xor(mx, 16));
      mx = fmaxf(mx, __shfl_xor(mx, 32));
      if (__any(mx > m[qs] + 8.0f)) {      // T13: skip rescale for small growth
        float mn = fmaxf(m[qs], mx);
        float al = fexp2(m[qs] - mn);
        m[qs] = mn;
        l[qs] *= al;
#pragma unroll
        for (int nt = 0; nt < 4; nt++) {
          o[qs][nt][0] *= al; o[qs][nt][1] *= al;
          o[qs][nt][2] *= al; o[qs][nt][3] *= al;
        }
      }
      float sm = 0.f;
      u32 wp[4][2];
#pragma unroll
      for (int f = 0; f < 4; f++) {
        float p0 = fexp2(st[qs][f][0] - m[qs]);
        float p1 = fexp2(st[qs][f][1] - m[qs]);
        float p2 = fexp2(st[qs][f][2] - m[qs]);
        float p3 = fexp2(st[qs][f][3] - m[qs]);
        sm += (p0 + p1) + (p2 + p3);
        wp[f][0] = packtrunc(p0, p1);
        wp[f][1] = packtrunc(p2, p3);
      }
      sm += __shfl_xor(sm, 16);
      sm += __shfl_xor(sm, 32);
      l[qs] += sm;

      // redistribute P words across quad pairs; even quads keep f-low pair
#pragma unroll
      for (int kh = 0; kh < 2; kh++) {
        const int flo = kh * 2, fhi = flo + 1;
        u32 tx0 = (quad & 1) ? wp[flo][0] : wp[fhi][0];
        u32 tx1 = (quad & 1) ? wp[flo][1] : wp[fhi][1];
        u32 rx0 = __shfl_xor(tx0, 16);
        u32 rx1 = __shfl_xor(tx1, 16);
        uint4 fw;
        fw.x = (quad & 1) ? rx0 : wp[flo][0];
        fw.y = (quad & 1) ? rx1 : wp[flo][1];
        fw.z = (quad & 1) ? wp[fhi][0] : rx0;
        fw.w = (quad & 1) ? wp[fhi][1] : rx1;
        bf16x8 pf = __builtin_bit_cast(bf16x8, fw);
#pragma unroll
        for (int nt = 0; nt < 4; nt++)
          o[qs][nt] = MFMA16(vf[nt][kh], pf, o[qs][nt]);
      }
    }
  }

  // ---- epilogue: write unnormalized partial O (fp32) + (m,l) per q-row ----
  float* oDst = kz ? oP1 : oP0;
  float* mlDst = kz ? ml1 : ml0;
#pragma unroll
  for (int qs = 0; qs < 2; qs++) {
    const long row = (long)bh * 2048 + qbase + qs * 16 + l16;
#pragma unroll
    for (int nt = 0; nt < 4; nt++)
      *(float4*)(oDst + row * 64 + nt * 16 + quad * 4) =
          *(const float4*)&o[qs][nt];
    if (quad == 0) {
      float2 ml2 = {m[qs], l[qs]};
      *(float2*)(mlDst + row * 2) = ml2;
    }
  }
}

// ---------------- merge the two key-halves -> ctx bf16 ----------------------
__global__ __launch_bounds__(256) void attn_combine_k(
    const float* __restrict__ o0, const float* __restrict__ o1,
    const float* __restrict__ ml0, const float* __restrict__ ml1,
    u16* __restrict__ ctx) {
  long i = ((long)blockIdx.x * 256 + threadIdx.x) * 4;  // element index
  long row = i >> 6;             // bh*2048 + ll
  int d = (int)(i & 63);
  float2 a0 = *(const float2*)(ml0 + row * 2);
  float2 a1 = *(const float2*)(ml1 + row * 2);
  float M = fmaxf(a0.x, a1.x);
  float w0 = fexp2(a0.x - M), w1 = fexp2(a1.x - M);
  float rinv = 1.0f / (a0.y * w0 + a1.y * w1);
  float4 v0 = *(const float4*)(o0 + i);
  float4 v1 = *(const float4*)(o1 + i);
  int bh = (int)(row >> 11), ll = (int)(row & 2047);
  int bI = bh >> 4, hh = bh & 15;
  ushort4 w;
  w.x = f2bf((v0.x * w0 + v1.x * w1) * rinv);
  w.y = f2bf((v0.y * w0 + v1.y * w1) * rinv);
  w.z = f2bf((v0.z * w0 + v1.z * w1) * rinv);
  w.w = f2bf((v0.w * w0 + v1.w * w1) * rinv);
  *(ushort4*)(ctx + ((long)(bI * 2048 + ll) * 1024) + hh * 64 + d) = w;
}

// ---------------- residual + LayerNorm -------------------------------------
__global__ __launch_bounds__(256) void ln_k(const float* __restrict__ a,
                                            const float* __restrict__ b,
                                            const float* __restrict__ g,
                                            const float* __restrict__ be,
                                            float* __restrict__ outF,
                                            u16* __restrict__ outB) {
  const int row = blockIdx.x, tid = threadIdx.x;
  const float* pa = a + (long)row * 1024;
  const float* pb = b + (long)row * 1024;
  float v[4], s = 0.f, sq = 0.f;
#pragma unroll
  for (int i = 0; i < 4; i++) {
    int c = i * 256 + tid;
    v[i] = pa[c] + pb[c];
    s += v[i];
    sq += v[i] * v[i];
  }
#pragma unroll
  for (int off = 1; off < 64; off <<= 1) {
    s += __shfl_xor(s, off);
    sq += __shfl_xor(sq, off);
  }
  __shared__ float red[10];
  int wave = tid >> 6, lane = tid & 63;
  if (lane == 0) { red[wave * 2] = s; red[wave * 2 + 1] = sq; }
  __syncthreads();
  if (tid == 0) {
    float S = red[0] + red[2] + red[4] + red[6];
    float Q = red[1] + red[3] + red[5] + red[7];
    float mu = S * (1.0f / 1024.0f);
    float var = Q * (1.0f / 1024.0f) - mu * mu;
    red[8] = mu;
    red[9] = rsqrtf(var + 1e-5f);
  }
  __syncthreads();
  float mu = red[8], rstd = red[9];
#pragma unroll
  for (int i = 0; i < 4; i++) {
    int c = i * 256 + tid;
    float o = (v[i] - mu) * rstd * g[c] + be[c];
    outF[(long)row * 1024 + c] = o;
    if (outB) outB[(long)row * 1024 + c] = f2bf(o);
  }
}

// ---- residual + 4-slab split-K reduce + bias + LayerNorm (LN2) ------------
__global__ __launch_bounds__(256) void ln4b_k(const float* __restrict__ a,
                                              const float* __restrict__ q0,
                                              const float* __restrict__ q1,
                                              const float* __restrict__ q2,
                                              const float* __restrict__ q3,
                                              const float* __restrict__ bias,
                                              const float* __restrict__ g,
                                              const float* __restrict__ be,
                                              float* __restrict__ outF) {
  const int row = blockIdx.x, tid = threadIdx.x;
  const long base = (long)row * 1024;
  float v[4], s = 0.f, sq = 0.f;
#pragma unroll
  for (int i = 0; i < 4; i++) {
    int c = i * 256 + tid;
    float ff = (q0[base + c] + q1[base + c]) + (q2[base + c] + q3[base + c]) + bias[c];
    v[i] = a[base + c] + ff;
    s += v[i];
    sq += v[i] * v[i];
  }
#pragma unroll
  for (int off = 1; off < 64; off <<= 1) {
    s += __shfl_xor(s, off);
    sq += __shfl_xor(sq, off);
  }
  __shared__ float red[10];
  int wave = tid >> 6, lane = tid & 63;
  if (lane == 0) { red[wave * 2] = s; red[wave * 2 + 1] = sq; }
  __syncthreads();
  if (tid == 0) {
    float S = red[0] + red[2] + red[4] + red[6];
    float Q = red[1] + red[3] + red[5] + red[7];
    float mu = S * (1.0f / 1024.0f);
    float var = Q * (1.0f / 1024.0f) - mu * mu;
    red[8] = mu;
    red[9] = rsqrtf(var + 1e-5f);
  }
  __syncthreads();
  float mu = red[8], rstd = red[9];
#pragma unroll
  for (int i = 0; i < 4; i++) {
    int c = i * 256 + tid;
    outF[base + c] = (v[i] - mu) * rstd * g[c] + be[c];
  }
}

// ---------------------------------------------------------------------------
extern "C" void kernel_launch(void* const* d_in, const int* in_sizes, int n_in,
                              void* d_out, int out_size, void* d_ws, size_t ws_size,
                              hipStream_t stream) {
  const float* x  = (const float*)d_in[0];
  const float* Wq = (const float*)d_in[1];  const float* bq = (const float*)d_in[2];
  const float* Wk = (const float*)d_in[3];  const float* bk = (const float*)d_in[4];
  const float* Wv = (const float*)d_in[5];  const float* bv = (const float*)d_in[6];
  const float* Wo = (const float*)d_in[7];  const float* bo = (const float*)d_in[8];
  const float* W1 = (const float*)d_in[9];  const float* b1 = (const float*)d_in[10];
  const float* W2 = (const float*)d_in[11]; const float* b2 = (const float*)d_in[12];
  const float* g1 = (const float*)d_in[13]; const float* be1 = (const float*)d_in[14];
  const float* g2 = (const float*)d_in[15]; const float* be2 = (const float*)d_in[16];

  char* ws = (char*)d_ws;
  size_t off = 0;
  auto alloc = [&](size_t bytes) {
    size_t o = off;
    off += (bytes + 255) & ~(size_t)255;
    return o;
  };
  u16*   xb     = (u16*)(ws + alloc(4096UL * 1024 * 2));
  u16*   wqkvT  = (u16*)(ws + alloc(3072UL * 1024 * 2));
  u16*   woT    = (u16*)(ws + alloc(1024UL * 1024 * 2));
  u16*   w1T    = (u16*)(ws + alloc(4096UL * 1024 * 2));
  u16*   w2T    = (u16*)(ws + alloc(1024UL * 4096 * 2));
  u16*   qb     = (u16*)(ws + alloc(32UL * 2048 * 64 * 2));   // 8 MiB
  u16*   kb     = (u16*)(ws + alloc(32UL * 2048 * 64 * 2));   // 8 MiB (contig after qb)
  u16*   vTb    = (u16*)(ws + alloc(32UL * 64 * 2048 * 2));   // 8 MiB (contig)
  u16*   ctx    = (u16*)(ws + alloc(4096UL * 1024 * 2));      // 8 MiB (contig after vTb)
  float* attnO  = (float*)(ws + alloc(4096UL * 1024 * 4));    // 16 MiB
  float* h      = (float*)(ws + alloc(4096UL * 1024 * 4));    // 16 MiB
  u16*   hb     = (u16*)(ws + alloc(4096UL * 1024 * 2));      // 8 MiB
  u16*   ff1    = (u16*)(ws + alloc(4096UL * 4096 * 2));      // 32 MiB
  float* ff2    = (float*)(ws + alloc(4096UL * 1024 * 4));    // 16 MiB
  if (off > ws_size) return;  // workspace too small: bail (bench will flag)

  // attention partials (alias regions dead during steps 3/3.5):
  float* oPart0 = attnO;            // read by combine before Wo writes attnO
  float* oPart1 = h;                // h written at step 5
  float* mlP0   = (float*)hb;       // hb written at step 5
  float* mlP1   = (float*)hb + 32 * 2048 * 2;

  // FFN-down split-K=4 slabs (dead regions during step 7):
  float* sl0 = ff2;
  float* sl1 = attnO;
  float* sl2 = (float*)qb;    // covers qb+kb (16 MiB contiguous)
  float* sl3 = (float*)vTb;   // covers vTb+ctx (16 MiB contiguous)

  // 1) bf16 conversions / weight transposes
  cvt_bf16_k<<<4096, 256, 0, stream>>>(x, xb);
  transpose4_bf16_k<<<dim3(32, 32, 4), 256, 0, stream>>>(Wq, Wk, Wv, Wo, wqkvT, woT);
  transpose_bf16_k<<<dim3(128, 32), 256, 0, stream>>>(W1, w1T, 1024, 4096);
  transpose_bf16_k<<<dim3(32, 128), 256, 0, stream>>>(W2, w2T, 4096, 1024);

  // 2) QKV projection: 128^2 tile, 768 blocks (3/CU), scatter epilogue
  gemm128_qkv_k<<<dim3(24, 32), 256, 0, stream>>>(xb, wqkvT, qb, kb, vTb,
                                                  bq, bk, bv);
  // 3) attention: key-split 2 -> 1024 blocks, partial O + (m,l)
  attn_k<<<dim3(16, 32, 2), 256, 0, stream>>>(qb, kb, vTb,
                                              oPart0, oPart1, mlP0, mlP1);
  // 3.5) merge halves -> ctx (bf16)
  attn_combine_k<<<4096, 256, 0, stream>>>(oPart0, oPart1, mlP0, mlP1, ctx);
  // 4) output projection (legacy TN=64 kernel)
  gemm_k<1, 64><<<dim3(16, 32), 256, 0, stream>>>(ctx, woT, 4096, 1024, 1024,
                                                  bo, attnO);
  // 5) residual + LN1 (fp32 h + bf16 hb)
  ln_k<<<4096, 256, 0, stream>>>(x, attnO, g1, be1, h, hb);
  // 6) FFN up + GELU — 256^2 pipelined
  gemm256_k<2><<<dim3(16, 16), 512, 0, stream>>>(
      hb, w1T, 4096, 1024, 1024, 1024,
      b1, nullptr, ff1, nullptr, nullptr, nullptr);
  // 7) FFN down — 256^2 pipelined, split-K=4 partial slabs
  gemm256_k<3><<<dim3(4, 16, 4), 512, 0, stream>>>(
      ff1, w2T, 1024, 4096, 4096, 1024,
      nullptr, sl0, nullptr, sl1, sl2, sl3);
  // 8) residual + slab-reduce + b2 + LN2 -> out
  ln4b_k<<<4096, 256, 0, stream>>>(h, sl0, sl1, sl2, sl3, b2, g2, be2,
                                   (float*)d_out);
}

// Round 5
// 382.757 us; speedup vs baseline: 1.0975x; 1.0465x over previous
//
#include <hip/hip_runtime.h>
#include <cmath>

// ---------------------------------------------------------------------------
// EncoderLayer: x -> MHA -> +res -> LN1 -> FFN(GELU) -> +res -> LN2
// B=2 L=2048 D=1024 H=16 dk=64 F=4096  (M = B*L = 4096 rows)
// bf16 MFMA 16x16x32, fp32 accumulate, fp32 LN/residual.
//
// Round 5 changes:
//  * attn: revert to unified (no key-split, no combine kernel) with the
//    P-LDS bounce (r2 inner loop, 74us form) + T13 defer-max; writes ctx
//    bf16 directly. Removes 134 MB of partial-O traffic (~20us).
//  * FFN-up / FFN-down: moved from gemm256 (1 block/CU coverage) to the
//    gemm128 ring-3 counted-vmcnt structure (3 blocks/CU). FFN-down uses
//    split-K=2 (Kc=2048, 2 fp32 slabs) -> LN2 reads 2 slabs not 4.
//  * gemm256 removed; gemm128_k templated (0=QKV scatter, 2=GELU, 3=slab).
// ---------------------------------------------------------------------------

typedef unsigned short u16;
typedef unsigned int u32;
typedef __attribute__((ext_vector_type(8))) __bf16 bf16x8;
typedef __attribute__((ext_vector_type(4))) float f32x4;

#define MFMA16(a, b, c) __builtin_amdgcn_mfma_f32_16x16x32_bf16(a, b, c, 0, 0, 0)

__device__ __forceinline__ u16 f2bf(float f) {
  u32 u = __builtin_bit_cast(u32, f);
  u += 0x7fffu + ((u >> 16) & 1u);   // round-to-nearest-even
  return (u16)(u >> 16);
}

// truncation-pack two fp32 -> bf16x2 in ONE v_perm_b32
__device__ __forceinline__ u32 packtrunc(float lo, float hi) {
#if __has_builtin(__builtin_amdgcn_perm)
  return __builtin_amdgcn_perm(__builtin_bit_cast(u32, hi),
                               __builtin_bit_cast(u32, lo), 0x07060302u);
#else
  return (__builtin_bit_cast(u32, lo) >> 16) |
         (__builtin_bit_cast(u32, hi) & 0xFFFF0000u);
#endif
}

__device__ __forceinline__ bf16x8 ld_frag(const u16* p) {
  return __builtin_bit_cast(bf16x8, *(const uint4*)p);
}

__device__ __forceinline__ float fexp2(float x) {
#if __has_builtin(__builtin_amdgcn_exp2f)
  return __builtin_amdgcn_exp2f(x);
#else
  return exp2f(x);
#endif
}

// async global->LDS, 16B per lane; LDS dest = wave-uniform base + lane*16
__device__ __forceinline__ void gload16(const u16* g, u16* l) {
  __builtin_amdgcn_global_load_lds(
      (const __attribute__((address_space(1))) void*)g,
      (__attribute__((address_space(3))) void*)l, 16, 0, 0);
}

// counted waits: gate vmem retirement without draining the pipeline, and
// drain own LDS reads before buffer-recycling barriers.
#define WAITVL(N) asm volatile("s_waitcnt vmcnt(" #N ") lgkmcnt(0)" ::: "memory")
#define BAR() do { __builtin_amdgcn_s_barrier(); asm volatile("" ::: "memory"); } while (0)

// ---------------- fp32 -> bf16 elementwise convert (x) ----------------------
__global__ __launch_bounds__(256) void cvt_bf16_k(const float* __restrict__ src,
                                                  u16* __restrict__ dst) {
  int i = (blockIdx.x * 256 + threadIdx.x) * 4;
  float4 v = *(const float4*)(src + i);
  ushort4 o;
  o.x = f2bf(v.x); o.y = f2bf(v.y); o.z = f2bf(v.z); o.w = f2bf(v.w);
  *(ushort4*)(dst + i) = o;
}

// ---------------- fp32 [R][C] -> bf16 [C][R] transpose ----------------------
__global__ __launch_bounds__(256) void transpose_bf16_k(const float* __restrict__ src,
                                                        u16* __restrict__ dst,
                                                        int R, int C) {
  __shared__ float tile[32][33];
  int tx = threadIdx.x & 31, ty = threadIdx.x >> 5;  // 32 x 8
  int c0 = blockIdx.x * 32, r0 = blockIdx.y * 32;
#pragma unroll
  for (int i = 0; i < 4; i++)
    tile[ty + 8 * i][tx] = src[(long)(r0 + ty + 8 * i) * C + c0 + tx];
  __syncthreads();
#pragma unroll
  for (int i = 0; i < 4; i++)
    dst[(long)(c0 + ty + 8 * i) * R + r0 + tx] = f2bf(tile[tx][ty + 8 * i]);
}

// ---- 4x 1024x1024 fp32 -> bf16 transposes in one launch (z picks matrix) ---
__global__ __launch_bounds__(256) void transpose4_bf16_k(
    const float* __restrict__ Wq, const float* __restrict__ Wk,
    const float* __restrict__ Wv, const float* __restrict__ Wo,
    u16* __restrict__ wqkvT, u16* __restrict__ woT) {
  const int z = blockIdx.z;
  const float* src = (z == 0) ? Wq : (z == 1) ? Wk : (z == 2) ? Wv : Wo;
  u16* dst = (z < 3) ? (wqkvT + (size_t)z * 1024 * 1024) : woT;
  __shared__ float tile[32][33];
  int tx = threadIdx.x & 31, ty = threadIdx.x >> 5;
  int c0 = blockIdx.x * 32, r0 = blockIdx.y * 32;
#pragma unroll
  for (int i = 0; i < 4; i++)
    tile[ty + 8 * i][tx] = src[(long)(r0 + ty + 8 * i) * 1024 + c0 + tx];
  __syncthreads();
#pragma unroll
  for (int i = 0; i < 4; i++)
    dst[(long)(c0 + ty + 8 * i) * 1024 + r0 + tx] = f2bf(tile[tx][ty + 8 * i]);
}

// ---------------------------------------------------------------------------
// gemm128: C[..] = A[M][lda-K] * BT[N][ldb-K]^T over Kc cols from kz*Kc.
// 128x128 tile, BK=32, 4 waves (2x2), per-wave 64x64 (4x4 frags).
// LDS ring-3 (A+B 16 KiB/tile = 48 KiB) -> 3 blocks/CU with (256,3).
// stage(t+2) issued during tile t; gate = WAITVL(4) (own stage(t) retired;
// stage(t+1) in flight) + BAR. Single barrier per K-tile, no drain.
// Buffer (t+2)%3 == (t-1)%3 is safe: readers of t-1 drained lgkm before BAR.
// MODE 0: QKV scatter epilogue; MODE 2: bias+GELU->bf16; MODE 3: fp32 slab.
// ---------------------------------------------------------------------------
template <int MODE>
__global__ __launch_bounds__(256, 3) void gemm128_k(
    const u16* __restrict__ A, const u16* __restrict__ BT,
    int N, int lda, int ldb, int Kc,
    const float* __restrict__ bias, float* __restrict__ outF,
    u16* __restrict__ outB, float* __restrict__ p1,
    u16* __restrict__ qd, u16* __restrict__ kd, u16* __restrict__ vTd,
    const float* __restrict__ bq, const float* __restrict__ bk,
    const float* __restrict__ bv) {
  __shared__ u16 As[3][128 * 32];   // 24 KiB
  __shared__ u16 Bs[3][128 * 32];   // 24 KiB
  const int tid = threadIdx.x;
  const int wave = tid >> 6, lane = tid & 63, quad = lane >> 4, l16 = lane & 15;
  const int wm = wave >> 1, wn = wave & 1;
  const int m0 = blockIdx.y * 128, n0 = blockIdx.x * 128;
  const int kz = blockIdx.z;
  const long kofs = (long)kz * Kc;
  const int KT = Kc >> 5;

  // staging: per wave 2 A-issues + 2 B-issues (16 rows x 64B each);
  // global source seg pre-XORed so linear LDS + XOR read line up.
  const int srow = lane >> 2;
  const int sseg = (lane & 3) ^ (srow & 3);
  const u16* aS = A + (long)(m0 + wave * 32 + srow) * lda + kofs + sseg * 8;
  const u16* bS = BT + (long)(n0 + wave * 32 + srow) * ldb + kofs + sseg * 8;

  auto stage = [&](int sb, int s) {
    const u16* pa = aS + (long)s * 32;
    gload16(pa, &As[sb][wave * 1024]);
    gload16(pa + 16 * (long)lda, &As[sb][wave * 1024 + 512]);
    const u16* pb = bS + (long)s * 32;
    gload16(pb, &Bs[sb][wave * 1024]);
    gload16(pb + 16 * (long)ldb, &Bs[sb][wave * 1024 + 512]);
  };

  int aro[4], bro[4];
#pragma unroll
  for (int f = 0; f < 4; f++) {
    int ra = wm * 64 + f * 16 + l16;
    aro[f] = ra * 32 + ((quad ^ (ra & 3)) * 8);
    int rb = wn * 64 + f * 16 + l16;
    bro[f] = rb * 32 + ((quad ^ (rb & 3)) * 8);
  }

  f32x4 acc[4][4] = {};

  stage(0, 0);
  stage(1, 1);
  int buf = 0;
#pragma unroll 1
  for (int t = 0; t < KT; ++t) {
    if (t < KT - 1) { WAITVL(4); } else { WAITVL(0); }
    BAR();
    bf16x8 af[4], bfr[4];
#pragma unroll
    for (int i = 0; i < 4; i++) af[i] = ld_frag(&As[buf][aro[i]]);
#pragma unroll
    for (int i = 0; i < 4; i++) bfr[i] = ld_frag(&Bs[buf][bro[i]]);
    if (t + 2 < KT) {
      int nb = buf + 2; if (nb >= 3) nb -= 3;
      stage(nb, t + 2);
    }
    __builtin_amdgcn_s_setprio(1);
#pragma unroll
    for (int mf = 0; mf < 4; mf++)
#pragma unroll
      for (int nf = 0; nf < 4; nf++)
        acc[mf][nf] = MFMA16(af[mf], bfr[nf], acc[mf][nf]);
    __builtin_amdgcn_s_setprio(0);
    if (++buf == 3) buf = 0;
  }

  if (MODE == 0) {
    // scatter epilogue (q: folded exp2 scale; k: plain; v: transposed)
    const int nbase = n0 + wn * 64;            // wave-uniform
    const int mat = nbase >> 10;               // 0=q 1=k 2=v
    const float* bp = (mat == 0) ? bq : ((mat == 1) ? bk : bv);
    float bb[4];
    int hh0[4], dd0[4];
#pragma unroll
    for (int nf = 0; nf < 4; nf++) {
      int nn = (nbase + nf * 16 + l16) & 1023;
      bb[nf] = bp[nn];
      hh0[nf] = nn >> 6;
      dd0[nf] = nn & 63;
    }
    if (mat < 2) {
#pragma unroll
      for (int mf = 0; mf < 4; mf++) {
#pragma unroll
        for (int r = 0; r < 4; r++) {
          int mr = m0 + wm * 64 + mf * 16 + quad * 4 + r;
          int bI = mr >> 11, ll = mr & 2047;
#pragma unroll
          for (int nf = 0; nf < 4; nf++) {
            float v = acc[mf][nf][r] + bb[nf];
            long idx = ((long)((bI * 16 + hh0[nf]) * 2048 + ll)) * 64 + dd0[nf];
            if (mat == 0) {
              qd[idx] = f2bf(v * 0.18033688011112043f);  // 1/sqrt(dk)*log2(e)
            } else {
              kd[idx] = f2bf(v);
            }
          }
        }
      }
    } else {
#pragma unroll
      for (int nf = 0; nf < 4; nf++) {
#pragma unroll
        for (int mf = 0; mf < 4; mf++) {
#pragma unroll
          for (int r = 0; r < 4; r++) {
            int mr = m0 + wm * 64 + mf * 16 + quad * 4 + r;
            int bI = mr >> 11, ll = mr & 2047;
            float v = acc[mf][nf][r] + bb[nf];
            vTd[((long)((bI * 16 + hh0[nf]) * 64 + dd0[nf])) * 2048 + ll] = f2bf(v);
          }
        }
      }
    }
  } else if (MODE == 2) {
    float bb[4];
#pragma unroll
    for (int nf = 0; nf < 4; nf++) bb[nf] = bias[n0 + wn * 64 + nf * 16 + l16];
#pragma unroll
    for (int mf = 0; mf < 4; mf++) {
#pragma unroll
      for (int r = 0; r < 4; r++) {
        int mr = m0 + wm * 64 + mf * 16 + quad * 4 + r;
        u16* orow = outB + (long)mr * N + n0 + wn * 64 + l16;
#pragma unroll
        for (int nf = 0; nf < 4; nf++) {
          float v = acc[mf][nf][r] + bb[nf];
          v = 0.5f * v * (1.0f + erff(v * 0.70710678118654752f));  // exact GELU
          orow[nf * 16] = f2bf(v);
        }
      }
    }
  } else {  // MODE 3: fp32 partial slab per kz (bias folded into LN reduce)
    float* sl = (kz == 0) ? outF : p1;
#pragma unroll
    for (int mf = 0; mf < 4; mf++) {
#pragma unroll
      for (int r = 0; r < 4; r++) {
        int mr = m0 + wm * 64 + mf * 16 + quad * 4 + r;
        float* orow = sl + (long)mr * N + n0 + wn * 64 + l16;
#pragma unroll
        for (int nf = 0; nf < 4; nf++) orow[nf * 16] = acc[mf][nf][r];
      }
    }
  }
}

// ---------------- GEMM: C[M][N] = A[M][K] * BT[N][K]^T (legacy, Wo only) ----
template <int MODE, int TN>
__global__ __launch_bounds__(256) void gemm_k(
    const u16* __restrict__ A, const u16* __restrict__ BT, int M, int N, int K,
    const float* __restrict__ bias, float* __restrict__ outF) {
  constexpr int NT = TN / 32;           // n-tiles per wave (4 or 2)
  __shared__ u16 As[2][128 * 32];
  __shared__ u16 Bs[2][TN * 32];
  const int tid = threadIdx.x;
  const int wave = tid >> 6, lane = tid & 63, quad = lane >> 4, l16 = lane & 15;
  const int wm = wave >> 1, wn = wave & 1;
  const int m0 = blockIdx.y * 128, n0 = blockIdx.x * TN;

  const int srow = lane >> 2;                  // 0..15
  const int sxor = (lane & 3) ^ (srow & 3);    // swizzled source seg
  const u16* aS0 = A + (long)(m0 + wave * 32 + srow) * K + sxor * 8;
  const u16* aS1 = aS0 + 16 * K;
  const u16* bS0 = BT + (long)(n0 + (TN == 128 ? wave * 32 : wave * 16) + srow) * K + sxor * 8;
  const u16* bS1 = bS0 + 16 * K;  // used only when TN==128

  int aoff[4], boff[NT];
#pragma unroll
  for (int t = 0; t < 4; t++) {
    int ra = wm * 64 + t * 16 + l16;
    aoff[t] = ra * 32 + ((quad ^ (l16 & 3)) * 8);
  }
#pragma unroll
  for (int t = 0; t < NT; t++) {
    int rb = wn * (TN / 2) + t * 16 + l16;
    boff[t] = rb * 32 + ((quad ^ (l16 & 3)) * 8);
  }

  auto stage = [&](int buf, int k0) {
    gload16(aS0 + k0, &As[buf][(wave * 2 + 0) * 512]);
    gload16(aS1 + k0, &As[buf][(wave * 2 + 1) * 512]);
    if (TN == 128) {
      gload16(bS0 + k0, &Bs[buf][(wave * 2 + 0) * 512]);
      gload16(bS1 + k0, &Bs[buf][(wave * 2 + 1) * 512]);
    } else {
      gload16(bS0 + k0, &Bs[buf][wave * 512]);
    }
  };

  f32x4 acc[4][NT] = {};

  stage(0, 0);
#pragma unroll 1
  for (int k0 = 0; k0 < K; k0 += 32) {
    const int buf = (k0 >> 5) & 1;
    __syncthreads();
    if (k0 + 32 < K) stage(buf ^ 1, k0 + 32);
    bf16x8 af[4], bfr[NT];
#pragma unroll
    for (int t = 0; t < 4; t++) af[t] = ld_frag(&As[buf][aoff[t]]);
#pragma unroll
    for (int t = 0; t < NT; t++) bfr[t] = ld_frag(&Bs[buf][boff[t]]);
#pragma unroll
    for (int mt = 0; mt < 4; mt++)
#pragma unroll
      for (int nt = 0; nt < NT; nt++)
        acc[mt][nt] = MFMA16(af[mt], bfr[nt], acc[mt][nt]);
  }

  if (MODE == 1) {
    float bb[NT];
#pragma unroll
    for (int nt = 0; nt < NT; nt++) bb[nt] = bias[n0 + wn * (TN / 2) + nt * 16 + l16];
#pragma unroll
    for (int mt = 0; mt < 4; mt++) {
#pragma unroll
      for (int r = 0; r < 4; r++) {
        int mr = m0 + wm * 64 + mt * 16 + quad * 4 + r;
        float* orow = outF + (long)mr * N + n0 + wn * (TN / 2) + l16;
#pragma unroll
        for (int nt = 0; nt < NT; nt++)
          orow[nt * 16] = acc[mt][nt][r] + bb[nt];
      }
    }
  }
}

// ---------------- flash attention (S^T, LDS-staged K/V, unified) ------------
// grid (L/128, B*H), 4 waves; wave owns 32 q rows (two 16-q sets); 64-key
// chunks over all 2048 keys. P^T bounced through padded LDS (proven fastest
// form: r2 74us vs in-reg-P 79us). T13 defer-max gate. Direct ctx write.
__global__ __launch_bounds__(256, 3) void attn_k(const u16* __restrict__ qd,
                                                 const u16* __restrict__ kd,
                                                 const u16* __restrict__ vTd,
                                                 u16* __restrict__ ctx) {
  __shared__ u16 Ks[2][64 * 64];
  __shared__ u16 Vs[2][64 * 64];
  __shared__ __align__(16) u16 P[4][32][72];  // per-wave P^T bounce
  const int tid = threadIdx.x;
  const int wave = tid >> 6, lane = tid & 63, quad = lane >> 4, l16 = lane & 15;
  const int bh = blockIdx.y;
  const u16* Q = qd + (long)bh * 2048 * 64;
  const u16* Kp = kd + (long)bh * 2048 * 64;
  const u16* Vt = vTd + (long)bh * 64 * 2048;
  const int qbase = blockIdx.x * 128 + wave * 32;

  // Q as B operand: lane holds Q[q=l16][d = quad*8+j], two q-sets x two halves
  bf16x8 qf[2][2];
#pragma unroll
  for (int qs = 0; qs < 2; qs++) {
    qf[qs][0] = ld_frag(Q + (qbase + qs * 16 + l16) * 64 + quad * 8);
    qf[qs][1] = ld_frag(Q + (qbase + qs * 16 + l16) * 64 + 32 + quad * 8);
  }

  f32x4 o[2][4] = {};              // O^T[d = nt*16+quad*4+r][q = l16] per set
  float m[2] = {-1e30f, -1e30f}, l[2] = {0.f, 0.f};

  // staging: issue i covers 8 rows (128B each): r = wave*16 + i*8 + lane/8
  const int srow = lane >> 3;                // 0..7
  const int sx = (lane & 7) ^ srow;          // swizzled source seg (16B units)
  const int kr0 = wave * 16 + srow;
  const int kr1 = wave * 16 + 8 + srow;

  // fragment seg offsets (u16 units): (g ^ (l16&7))*8
  const int fs0 = ((0 * 4 + quad) ^ (l16 & 7)) * 8;
  const int fs1 = ((1 * 4 + quad) ^ (l16 & 7)) * 8;

  auto stage = [&](int buf, int j0) {
    gload16(Kp + (long)(j0 + kr0) * 64 + sx * 8, &Ks[buf][(wave * 2 + 0) * 512]);
    gload16(Kp + (long)(j0 + kr1) * 64 + sx * 8, &Ks[buf][(wave * 2 + 1) * 512]);
    gload16(Vt + (long)kr0 * 2048 + j0 + sx * 8, &Vs[buf][(wave * 2 + 0) * 512]);
    gload16(Vt + (long)kr1 * 2048 + j0 + sx * 8, &Vs[buf][(wave * 2 + 1) * 512]);
  };

  stage(0, 0);

#pragma unroll 1
  for (int j0 = 0; j0 < 2048; j0 += 64) {
    const int buf = (j0 >> 6) & 1;
    __syncthreads();                       // staged chunk visible; prev body done
    if (j0 + 64 < 2048) stage(buf ^ 1, j0 + 64);

    // ---- S^T = K Q^T over 64 keys, both q-sets (K frags shared) ----
    const u16* kb = &Ks[buf][0];
    f32x4 st[2][4];
#pragma unroll
    for (int f = 0; f < 4; f++) {
      bf16x8 k0 = ld_frag(kb + (f * 16 + l16) * 64 + fs0);
      bf16x8 k1 = ld_frag(kb + (f * 16 + l16) * 64 + fs1);
      f32x4 s0 = {}, s1 = {};
      s0 = MFMA16(k0, qf[0][0], s0); s0 = MFMA16(k1, qf[0][1], s0);
      s1 = MFMA16(k0, qf[1][0], s1); s1 = MFMA16(k1, qf[1][1], s1);
      st[0][f] = s0; st[1][f] = s1;
    }

    // ---- online softmax per q-set (T13 defer-max) ----
#pragma unroll
    for (int qs = 0; qs < 2; qs++) {
      float mx = -1e30f;
#pragma unroll
      for (int f = 0; f < 4; f++)
        mx = fmaxf(mx, fmaxf(fmaxf(st[qs][f][0], st[qs][f][1]),
                             fmaxf(st[qs][f][2], st[qs][f][3])));
      mx = fmaxf(mx, __shfl_xor(mx, 16));
      mx = fmaxf(mx, __shfl_xor(mx, 32));
      if (__any(mx > m[qs] + 8.0f)) {      // skip rescale for small growth
        float mn = fmaxf(m[qs], mx);
        float al = fexp2(m[qs] - mn);
        m[qs] = mn;
        l[qs] *= al;
#pragma unroll
        for (int nt = 0; nt < 4; nt++) {
          o[qs][nt][0] *= al; o[qs][nt][1] *= al;
          o[qs][nt][2] *= al; o[qs][nt][3] *= al;
        }
      }
      float sm = 0.f;
      u16* prow = &P[wave][qs * 16 + l16][0];
#pragma unroll
      for (int f = 0; f < 4; f++) {
        float p0 = fexp2(st[qs][f][0] - m[qs]);
        float p1 = fexp2(st[qs][f][1] - m[qs]);
        float p2 = fexp2(st[qs][f][2] - m[qs]);
        float p3 = fexp2(st[qs][f][3] - m[qs]);
        sm += (p0 + p1) + (p2 + p3);
        uint2 u;
        u.x = packtrunc(p0, p1);
        u.y = packtrunc(p2, p3);
        *(uint2*)(prow + f * 16 + quad * 4) = u;
      }
      sm += __shfl_xor(sm, 16);
      sm += __shfl_xor(sm, 32);
      l[qs] += sm;
    }
    // wave-internal write->read ordering (no inter-wave dep, no barrier)
    __asm__ volatile("s_waitcnt lgkmcnt(0)" ::: "memory");

    // ---- O^T += V^T P^T (V frags shared across q-sets) ----
    const u16* vb = &Vs[buf][0];
    bf16x8 vf[4][2];
#pragma unroll
    for (int nt = 0; nt < 4; nt++) {
      vf[nt][0] = ld_frag(vb + (nt * 16 + l16) * 64 + fs0);
      vf[nt][1] = ld_frag(vb + (nt * 16 + l16) * 64 + fs1);
    }
#pragma unroll
    for (int qs = 0; qs < 2; qs++) {
      const u16* prow = &P[wave][qs * 16 + l16][0];
#pragma unroll
      for (int kh = 0; kh < 2; kh++) {
        bf16x8 pf = ld_frag(prow + kh * 32 + quad * 8);
#pragma unroll
        for (int nt = 0; nt < 4; nt++)
          o[qs][nt] = MFMA16(vf[nt][kh], pf, o[qs][nt]);
      }
    }
  }

  // ---- epilogue: divide by l, write ctx[b][l][h*64+d] ----
  const int bI = bh >> 4, hh = bh & 15;
#pragma unroll
  for (int qs = 0; qs < 2; qs++) {
    const float rl = 1.0f / l[qs];
    const long row = (long)(bI * 2048 + qbase + qs * 16 + l16);
#pragma unroll
    for (int nt = 0; nt < 4; nt++) {
      ushort4 w;
      w.x = f2bf(o[qs][nt][0] * rl);
      w.y = f2bf(o[qs][nt][1] * rl);
      w.z = f2bf(o[qs][nt][2] * rl);
      w.w = f2bf(o[qs][nt][3] * rl);
      *(ushort4*)(ctx + row * 1024 + hh * 64 + nt * 16 + quad * 4) = w;
    }
  }
}

// ---------------- residual + LayerNorm -------------------------------------
__global__ __launch_bounds__(256) void ln_k(const float* __restrict__ a,
                                            const float* __restrict__ b,
                                            const float* __restrict__ g,
                                            const float* __restrict__ be,
                                            float* __restrict__ outF,
                                            u16* __restrict__ outB) {
  const int row = blockIdx.x, tid = threadIdx.x;
  const float* pa = a + (long)row * 1024;
  const float* pb = b + (long)row * 1024;
  float v[4], s = 0.f, sq = 0.f;
#pragma unroll
  for (int i = 0; i < 4; i++) {
    int c = i * 256 + tid;
    v[i] = pa[c] + pb[c];
    s += v[i];
    sq += v[i] * v[i];
  }
#pragma unroll
  for (int off = 1; off < 64; off <<= 1) {
    s += __shfl_xor(s, off);
    sq += __shfl_xor(sq, off);
  }
  __shared__ float red[10];
  int wave = tid >> 6, lane = tid & 63;
  if (lane == 0) { red[wave * 2] = s; red[wave * 2 + 1] = sq; }
  __syncthreads();
  if (tid == 0) {
    float S = red[0] + red[2] + red[4] + red[6];
    float Q = red[1] + red[3] + red[5] + red[7];
    float mu = S * (1.0f / 1024.0f);
    float var = Q * (1.0f / 1024.0f) - mu * mu;
    red[8] = mu;
    red[9] = rsqrtf(var + 1e-5f);
  }
  __syncthreads();
  float mu = red[8], rstd = red[9];
#pragma unroll
  for (int i = 0; i < 4; i++) {
    int c = i * 256 + tid;
    float o = (v[i] - mu) * rstd * g[c] + be[c];
    outF[(long)row * 1024 + c] = o;
    if (outB) outB[(long)row * 1024 + c] = f2bf(o);
  }
}

// ---- residual + 2-slab split-K reduce + bias + LayerNorm (LN2) ------------
__global__ __launch_bounds__(256) void ln2s_k(const float* __restrict__ a,
                                              const float* __restrict__ q0,
                                              const float* __restrict__ q1,
                                              const float* __restrict__ bias,
                                              const float* __restrict__ g,
                                              const float* __restrict__ be,
                                              float* __restrict__ outF) {
  const int row = blockIdx.x, tid = threadIdx.x;
  const long base = (long)row * 1024;
  float v[4], s = 0.f, sq = 0.f;
#pragma unroll
  for (int i = 0; i < 4; i++) {
    int c = i * 256 + tid;
    float ff = q0[base + c] + q1[base + c] + bias[c];
    v[i] = a[base + c] + ff;
    s += v[i];
    sq += v[i] * v[i];
  }
#pragma unroll
  for (int off = 1; off < 64; off <<= 1) {
    s += __shfl_xor(s, off);
    sq += __shfl_xor(sq, off);
  }
  __shared__ float red[10];
  int wave = tid >> 6, lane = tid & 63;
  if (lane == 0) { red[wave * 2] = s; red[wave * 2 + 1] = sq; }
  __syncthreads();
  if (tid == 0) {
    float S = red[0] + red[2] + red[4] + red[6];
    float Q = red[1] + red[3] + red[5] + red[7];
    float mu = S * (1.0f / 1024.0f);
    float var = Q * (1.0f / 1024.0f) - mu * mu;
    red[8] = mu;
    red[9] = rsqrtf(var + 1e-5f);
  }
  __syncthreads();
  float mu = red[8], rstd = red[9];
#pragma unroll
  for (int i = 0; i < 4; i++) {
    int c = i * 256 + tid;
    outF[base + c] = (v[i] - mu) * rstd * g[c] + be[c];
  }
}

// ---------------------------------------------------------------------------
extern "C" void kernel_launch(void* const* d_in, const int* in_sizes, int n_in,
                              void* d_out, int out_size, void* d_ws, size_t ws_size,
                              hipStream_t stream) {
  const float* x  = (const float*)d_in[0];
  const float* Wq = (const float*)d_in[1];  const float* bq = (const float*)d_in[2];
  const float* Wk = (const float*)d_in[3];  const float* bk = (const float*)d_in[4];
  const float* Wv = (const float*)d_in[5];  const float* bv = (const float*)d_in[6];
  const float* Wo = (const float*)d_in[7];  const float* bo = (const float*)d_in[8];
  const float* W1 = (const float*)d_in[9];  const float* b1 = (const float*)d_in[10];
  const float* W2 = (const float*)d_in[11]; const float* b2 = (const float*)d_in[12];
  const float* g1 = (const float*)d_in[13]; const float* be1 = (const float*)d_in[14];
  const float* g2 = (const float*)d_in[15]; const float* be2 = (const float*)d_in[16];

  char* ws = (char*)d_ws;
  size_t off = 0;
  auto alloc = [&](size_t bytes) {
    size_t o = off;
    off += (bytes + 255) & ~(size_t)255;
    return o;
  };
  u16*   xb     = (u16*)(ws + alloc(4096UL * 1024 * 2));
  u16*   wqkvT  = (u16*)(ws + alloc(3072UL * 1024 * 2));
  u16*   woT    = (u16*)(ws + alloc(1024UL * 1024 * 2));
  u16*   w1T    = (u16*)(ws + alloc(4096UL * 1024 * 2));
  u16*   w2T    = (u16*)(ws + alloc(1024UL * 4096 * 2));
  u16*   qb     = (u16*)(ws + alloc(32UL * 2048 * 64 * 2));   // 8 MiB
  u16*   kb     = (u16*)(ws + alloc(32UL * 2048 * 64 * 2));   // 8 MiB
  u16*   vTb    = (u16*)(ws + alloc(32UL * 64 * 2048 * 2));   // 8 MiB
  u16*   ctx    = (u16*)(ws + alloc(4096UL * 1024 * 2));      // 8 MiB
  float* attnO  = (float*)(ws + alloc(4096UL * 1024 * 4));    // 16 MiB
  float* h      = (float*)(ws + alloc(4096UL * 1024 * 4));    // 16 MiB
  u16*   hb     = (u16*)(ws + alloc(4096UL * 1024 * 2));      // 8 MiB
  u16*   ff1    = (u16*)(ws + alloc(4096UL * 4096 * 2));      // 32 MiB
  float* ff2    = (float*)(ws + alloc(4096UL * 1024 * 4));    // 16 MiB
  if (off > ws_size) return;  // workspace too small: bail (bench will flag)

  // FFN-down split-K=2 slabs (regions dead during step 7):
  float* sl0 = ff2;
  float* sl1 = attnO;

  // 1) bf16 conversions / weight transposes
  cvt_bf16_k<<<4096, 256, 0, stream>>>(x, xb);
  transpose4_bf16_k<<<dim3(32, 32, 4), 256, 0, stream>>>(Wq, Wk, Wv, Wo, wqkvT, woT);
  transpose_bf16_k<<<dim3(128, 32), 256, 0, stream>>>(W1, w1T, 1024, 4096);
  transpose_bf16_k<<<dim3(32, 128), 256, 0, stream>>>(W2, w2T, 4096, 1024);

  // 2) QKV projection: 128^2 ring-3, 768 blocks (3/CU), scatter epilogue
  gemm128_k<0><<<dim3(24, 32), 256, 0, stream>>>(
      xb, wqkvT, 3072, 1024, 1024, 1024,
      nullptr, nullptr, nullptr, nullptr,
      qb, kb, vTb, bq, bk, bv);
  // 3) attention: unified (no split), direct ctx write
  attn_k<<<dim3(16, 32), 256, 0, stream>>>(qb, kb, vTb, ctx);
  // 4) output projection (legacy TN=64 kernel)
  gemm_k<1, 64><<<dim3(16, 32), 256, 0, stream>>>(ctx, woT, 4096, 1024, 1024,
                                                  bo, attnO);
  // 5) residual + LN1 (fp32 h + bf16 hb)
  ln_k<<<4096, 256, 0, stream>>>(x, attnO, g1, be1, h, hb);
  // 6) FFN up + GELU: 128^2 ring-3, 1024 blocks (3/CU)
  gemm128_k<2><<<dim3(32, 32), 256, 0, stream>>>(
      hb, w1T, 4096, 1024, 1024, 1024,
      b1, nullptr, ff1, nullptr,
      nullptr, nullptr, nullptr, nullptr, nullptr, nullptr);
  // 7) FFN down: 128^2 ring-3, split-K=2 (Kc=2048), 512 blocks
  gemm128_k<3><<<dim3(8, 32, 2), 256, 0, stream>>>(
      ff1, w2T, 1024, 4096, 4096, 2048,
      nullptr, sl0, nullptr, sl1,
      nullptr, nullptr, nullptr, nullptr, nullptr, nullptr);
  // 8) residual + 2-slab reduce + b2 + LN2 -> out
  ln2s_k<<<4096, 256, 0, stream>>>(h, sl0, sl1, b2, g2, be2, (float*)d_out);
}

// Round 6
// 370.957 us; speedup vs baseline: 1.1324x; 1.0318x over previous
//
#include <hip/hip_runtime.h>
#include <cmath>

// ---------------------------------------------------------------------------
// EncoderLayer: x -> MHA -> +res -> LN1 -> FFN(GELU) -> +res -> LN2
// B=2 L=2048 D=1024 H=16 dk=64 F=4096  (M = B*L = 4096 rows)
// bf16 MFMA 16x16x32, fp32 accumulate, fp32 LN/residual.
//
// Round 6 changes:
//  * MODE 2 epilogue: libm erff (branchy ~40 instr, both paths execute)
//    replaced with branch-free A&S 7.1.26 erf (5-term poly + rcp + exp2,
//    |err|<1.5e-7 -- invisible at bf16 output precision).
//  * gemm128: XCD-chunked bijective blockIdx swizzle (T1) -- all grids
//    are multiples of 8; contiguous work chunk per XCD -> L2 panel reuse.
//  * bank-conflict counter identified as global_load_lds write-burst
//    artifact (exactly 8 cyc/gload) -- not actionable.
// ---------------------------------------------------------------------------

typedef unsigned short u16;
typedef unsigned int u32;
typedef __attribute__((ext_vector_type(8))) __bf16 bf16x8;
typedef __attribute__((ext_vector_type(4))) float f32x4;

#define MFMA16(a, b, c) __builtin_amdgcn_mfma_f32_16x16x32_bf16(a, b, c, 0, 0, 0)

__device__ __forceinline__ u16 f2bf(float f) {
  u32 u = __builtin_bit_cast(u32, f);
  u += 0x7fffu + ((u >> 16) & 1u);   // round-to-nearest-even
  return (u16)(u >> 16);
}

// truncation-pack two fp32 -> bf16x2 in ONE v_perm_b32
__device__ __forceinline__ u32 packtrunc(float lo, float hi) {
#if __has_builtin(__builtin_amdgcn_perm)
  return __builtin_amdgcn_perm(__builtin_bit_cast(u32, hi),
                               __builtin_bit_cast(u32, lo), 0x07060302u);
#else
  return (__builtin_bit_cast(u32, lo) >> 16) |
         (__builtin_bit_cast(u32, hi) & 0xFFFF0000u);
#endif
}

__device__ __forceinline__ bf16x8 ld_frag(const u16* p) {
  return __builtin_bit_cast(bf16x8, *(const uint4*)p);
}

__device__ __forceinline__ float fexp2(float x) {
#if __has_builtin(__builtin_amdgcn_exp2f)
  return __builtin_amdgcn_exp2f(x);
#else
  return exp2f(x);
#endif
}

__device__ __forceinline__ float frcp(float x) {
#if __has_builtin(__builtin_amdgcn_rcpf)
  return __builtin_amdgcn_rcpf(x);
#else
  return 1.0f / x;
#endif
}

// exact-GELU via A&S 7.1.26 erf approximation: |err(erf)| < 1.5e-7,
// branch-free (large |v| saturates via exp2 underflow -> erf = +-1).
__device__ __forceinline__ float gelu_f(float v) {
  float x = v * 0.70710678118654752f;
  float a = fabsf(x);
  float t = frcp(fmaf(0.3275911f, a, 1.0f));
  float p = fmaf(1.061405429f, t, -1.453152027f);
  p = fmaf(p, t, 1.421413741f);
  p = fmaf(p, t, -0.284496736f);
  p = fmaf(p, t, 0.254829592f);
  p = p * t;
  float e = fexp2(-a * a * 1.4426950408889634f);
  float er = copysignf(1.0f - p * e, x);
  return 0.5f * v * (1.0f + er);
}

// async global->LDS, 16B per lane; LDS dest = wave-uniform base + lane*16
__device__ __forceinline__ void gload16(const u16* g, u16* l) {
  __builtin_amdgcn_global_load_lds(
      (const __attribute__((address_space(1))) void*)g,
      (__attribute__((address_space(3))) void*)l, 16, 0, 0);
}

// counted waits: gate vmem retirement without draining the pipeline, and
// drain own LDS reads before buffer-recycling barriers.
#define WAITVL(N) asm volatile("s_waitcnt vmcnt(" #N ") lgkmcnt(0)" ::: "memory")
#define BAR() do { __builtin_amdgcn_s_barrier(); asm volatile("" ::: "memory"); } while (0)

// ---------------- fp32 -> bf16 elementwise convert (x) ----------------------
__global__ __launch_bounds__(256) void cvt_bf16_k(const float* __restrict__ src,
                                                  u16* __restrict__ dst) {
  int i = (blockIdx.x * 256 + threadIdx.x) * 4;
  float4 v = *(const float4*)(src + i);
  ushort4 o;
  o.x = f2bf(v.x); o.y = f2bf(v.y); o.z = f2bf(v.z); o.w = f2bf(v.w);
  *(ushort4*)(dst + i) = o;
}

// ---------------- fp32 [R][C] -> bf16 [C][R] transpose ----------------------
__global__ __launch_bounds__(256) void transpose_bf16_k(const float* __restrict__ src,
                                                        u16* __restrict__ dst,
                                                        int R, int C) {
  __shared__ float tile[32][33];
  int tx = threadIdx.x & 31, ty = threadIdx.x >> 5;  // 32 x 8
  int c0 = blockIdx.x * 32, r0 = blockIdx.y * 32;
#pragma unroll
  for (int i = 0; i < 4; i++)
    tile[ty + 8 * i][tx] = src[(long)(r0 + ty + 8 * i) * C + c0 + tx];
  __syncthreads();
#pragma unroll
  for (int i = 0; i < 4; i++)
    dst[(long)(c0 + ty + 8 * i) * R + r0 + tx] = f2bf(tile[tx][ty + 8 * i]);
}

// ---- 4x 1024x1024 fp32 -> bf16 transposes in one launch (z picks matrix) ---
__global__ __launch_bounds__(256) void transpose4_bf16_k(
    const float* __restrict__ Wq, const float* __restrict__ Wk,
    const float* __restrict__ Wv, const float* __restrict__ Wo,
    u16* __restrict__ wqkvT, u16* __restrict__ woT) {
  const int z = blockIdx.z;
  const float* src = (z == 0) ? Wq : (z == 1) ? Wk : (z == 2) ? Wv : Wo;
  u16* dst = (z < 3) ? (wqkvT + (size_t)z * 1024 * 1024) : woT;
  __shared__ float tile[32][33];
  int tx = threadIdx.x & 31, ty = threadIdx.x >> 5;
  int c0 = blockIdx.x * 32, r0 = blockIdx.y * 32;
#pragma unroll
  for (int i = 0; i < 4; i++)
    tile[ty + 8 * i][tx] = src[(long)(r0 + ty + 8 * i) * 1024 + c0 + tx];
  __syncthreads();
#pragma unroll
  for (int i = 0; i < 4; i++)
    dst[(long)(c0 + ty + 8 * i) * 1024 + r0 + tx] = f2bf(tile[tx][ty + 8 * i]);
}

// ---------------------------------------------------------------------------
// gemm128: C[..] = A[M][lda-K] * BT[N][ldb-K]^T over Kc cols from kz*Kc.
// 128x128 tile, BK=32, 4 waves (2x2), per-wave 64x64 (4x4 frags).
// LDS ring-3 (A+B 16 KiB/tile = 48 KiB) -> 3 blocks/CU with (256,3).
// stage(t+2) issued during tile t; gate = WAITVL(4) (own stage(t) retired;
// stage(t+1) in flight) + BAR. Single barrier per K-tile, no drain.
// XCD-chunked bijective block swizzle (grid x*y must be %8==0).
// MODE 0: QKV scatter epilogue; MODE 2: bias+GELU->bf16; MODE 3: fp32 slab.
// ---------------------------------------------------------------------------
template <int MODE>
__global__ __launch_bounds__(256, 3) void gemm128_k(
    const u16* __restrict__ A, const u16* __restrict__ BT,
    int N, int lda, int ldb, int Kc,
    const float* __restrict__ bias, float* __restrict__ outF,
    u16* __restrict__ outB, float* __restrict__ p1,
    u16* __restrict__ qd, u16* __restrict__ kd, u16* __restrict__ vTd,
    const float* __restrict__ bq, const float* __restrict__ bk,
    const float* __restrict__ bv) {
  __shared__ u16 As[3][128 * 32];   // 24 KiB
  __shared__ u16 Bs[3][128 * 32];   // 24 KiB
  const int tid = threadIdx.x;
  const int wave = tid >> 6, lane = tid & 63, quad = lane >> 4, l16 = lane & 15;
  const int wm = wave >> 1, wn = wave & 1;
  // XCD-chunked bijective remap: contiguous work chunk per XCD (nwg%8==0)
  const int gx = gridDim.x;
  int flat = blockIdx.y * gx + blockIdx.x;
  const int cpx = (gx * gridDim.y) >> 3;
  flat = (flat & 7) * cpx + (flat >> 3);
  const int m0 = (flat / gx) * 128, n0 = (flat % gx) * 128;
  const int kz = blockIdx.z;
  const long kofs = (long)kz * Kc;
  const int KT = Kc >> 5;

  // staging: per wave 2 A-issues + 2 B-issues (16 rows x 64B each);
  // global source seg pre-XORed so linear LDS + XOR read line up.
  const int srow = lane >> 2;
  const int sseg = (lane & 3) ^ (srow & 3);
  const u16* aS = A + (long)(m0 + wave * 32 + srow) * lda + kofs + sseg * 8;
  const u16* bS = BT + (long)(n0 + wave * 32 + srow) * ldb + kofs + sseg * 8;

  auto stage = [&](int sb, int s) {
    const u16* pa = aS + (long)s * 32;
    gload16(pa, &As[sb][wave * 1024]);
    gload16(pa + 16 * (long)lda, &As[sb][wave * 1024 + 512]);
    const u16* pb = bS + (long)s * 32;
    gload16(pb, &Bs[sb][wave * 1024]);
    gload16(pb + 16 * (long)ldb, &Bs[sb][wave * 1024 + 512]);
  };

  int aro[4], bro[4];
#pragma unroll
  for (int f = 0; f < 4; f++) {
    int ra = wm * 64 + f * 16 + l16;
    aro[f] = ra * 32 + ((quad ^ (ra & 3)) * 8);
    int rb = wn * 64 + f * 16 + l16;
    bro[f] = rb * 32 + ((quad ^ (rb & 3)) * 8);
  }

  f32x4 acc[4][4] = {};

  stage(0, 0);
  stage(1, 1);
  int buf = 0;
#pragma unroll 1
  for (int t = 0; t < KT; ++t) {
    if (t < KT - 1) { WAITVL(4); } else { WAITVL(0); }
    BAR();
    bf16x8 af[4], bfr[4];
#pragma unroll
    for (int i = 0; i < 4; i++) af[i] = ld_frag(&As[buf][aro[i]]);
#pragma unroll
    for (int i = 0; i < 4; i++) bfr[i] = ld_frag(&Bs[buf][bro[i]]);
    if (t + 2 < KT) {
      int nb = buf + 2; if (nb >= 3) nb -= 3;
      stage(nb, t + 2);
    }
    __builtin_amdgcn_s_setprio(1);
#pragma unroll
    for (int mf = 0; mf < 4; mf++)
#pragma unroll
      for (int nf = 0; nf < 4; nf++)
        acc[mf][nf] = MFMA16(af[mf], bfr[nf], acc[mf][nf]);
    __builtin_amdgcn_s_setprio(0);
    if (++buf == 3) buf = 0;
  }

  if (MODE == 0) {
    // scatter epilogue (q: folded exp2 scale; k: plain; v: transposed)
    const int nbase = n0 + wn * 64;            // wave-uniform
    const int mat = nbase >> 10;               // 0=q 1=k 2=v
    const float* bp = (mat == 0) ? bq : ((mat == 1) ? bk : bv);
    float bb[4];
    int hh0[4], dd0[4];
#pragma unroll
    for (int nf = 0; nf < 4; nf++) {
      int nn = (nbase + nf * 16 + l16) & 1023;
      bb[nf] = bp[nn];
      hh0[nf] = nn >> 6;
      dd0[nf] = nn & 63;
    }
    if (mat < 2) {
#pragma unroll
      for (int mf = 0; mf < 4; mf++) {
#pragma unroll
        for (int r = 0; r < 4; r++) {
          int mr = m0 + wm * 64 + mf * 16 + quad * 4 + r;
          int bI = mr >> 11, ll = mr & 2047;
#pragma unroll
          for (int nf = 0; nf < 4; nf++) {
            float v = acc[mf][nf][r] + bb[nf];
            long idx = ((long)((bI * 16 + hh0[nf]) * 2048 + ll)) * 64 + dd0[nf];
            if (mat == 0) {
              qd[idx] = f2bf(v * 0.18033688011112043f);  // 1/sqrt(dk)*log2(e)
            } else {
              kd[idx] = f2bf(v);
            }
          }
        }
      }
    } else {
#pragma unroll
      for (int nf = 0; nf < 4; nf++) {
#pragma unroll
        for (int mf = 0; mf < 4; mf++) {
#pragma unroll
          for (int r = 0; r < 4; r++) {
            int mr = m0 + wm * 64 + mf * 16 + quad * 4 + r;
            int bI = mr >> 11, ll = mr & 2047;
            float v = acc[mf][nf][r] + bb[nf];
            vTd[((long)((bI * 16 + hh0[nf]) * 64 + dd0[nf])) * 2048 + ll] = f2bf(v);
          }
        }
      }
    }
  } else if (MODE == 2) {
    float bb[4];
#pragma unroll
    for (int nf = 0; nf < 4; nf++) bb[nf] = bias[n0 + wn * 64 + nf * 16 + l16];
#pragma unroll
    for (int mf = 0; mf < 4; mf++) {
#pragma unroll
      for (int r = 0; r < 4; r++) {
        int mr = m0 + wm * 64 + mf * 16 + quad * 4 + r;
        u16* orow = outB + (long)mr * N + n0 + wn * 64 + l16;
#pragma unroll
        for (int nf = 0; nf < 4; nf++)
          orow[nf * 16] = f2bf(gelu_f(acc[mf][nf][r] + bb[nf]));
      }
    }
  } else {  // MODE 3: fp32 partial slab per kz (bias folded into LN reduce)
    float* sl = (kz == 0) ? outF : p1;
#pragma unroll
    for (int mf = 0; mf < 4; mf++) {
#pragma unroll
      for (int r = 0; r < 4; r++) {
        int mr = m0 + wm * 64 + mf * 16 + quad * 4 + r;
        float* orow = sl + (long)mr * N + n0 + wn * 64 + l16;
#pragma unroll
        for (int nf = 0; nf < 4; nf++) orow[nf * 16] = acc[mf][nf][r];
      }
    }
  }
}

// ---------------- GEMM: C[M][N] = A[M][K] * BT[N][K]^T (legacy, Wo only) ----
template <int MODE, int TN>
__global__ __launch_bounds__(256) void gemm_k(
    const u16* __restrict__ A, const u16* __restrict__ BT, int M, int N, int K,
    const float* __restrict__ bias, float* __restrict__ outF) {
  constexpr int NT = TN / 32;           // n-tiles per wave (4 or 2)
  __shared__ u16 As[2][128 * 32];
  __shared__ u16 Bs[2][TN * 32];
  const int tid = threadIdx.x;
  const int wave = tid >> 6, lane = tid & 63, quad = lane >> 4, l16 = lane & 15;
  const int wm = wave >> 1, wn = wave & 1;
  const int m0 = blockIdx.y * 128, n0 = blockIdx.x * TN;

  const int srow = lane >> 2;                  // 0..15
  const int sxor = (lane & 3) ^ (srow & 3);    // swizzled source seg
  const u16* aS0 = A + (long)(m0 + wave * 32 + srow) * K + sxor * 8;
  const u16* aS1 = aS0 + 16 * K;
  const u16* bS0 = BT + (long)(n0 + (TN == 128 ? wave * 32 : wave * 16) + srow) * K + sxor * 8;
  const u16* bS1 = bS0 + 16 * K;  // used only when TN==128

  int aoff[4], boff[NT];
#pragma unroll
  for (int t = 0; t < 4; t++) {
    int ra = wm * 64 + t * 16 + l16;
    aoff[t] = ra * 32 + ((quad ^ (l16 & 3)) * 8);
  }
#pragma unroll
  for (int t = 0; t < NT; t++) {
    int rb = wn * (TN / 2) + t * 16 + l16;
    boff[t] = rb * 32 + ((quad ^ (l16 & 3)) * 8);
  }

  auto stage = [&](int buf, int k0) {
    gload16(aS0 + k0, &As[buf][(wave * 2 + 0) * 512]);
    gload16(aS1 + k0, &As[buf][(wave * 2 + 1) * 512]);
    if (TN == 128) {
      gload16(bS0 + k0, &Bs[buf][(wave * 2 + 0) * 512]);
      gload16(bS1 + k0, &Bs[buf][(wave * 2 + 1) * 512]);
    } else {
      gload16(bS0 + k0, &Bs[buf][wave * 512]);
    }
  };

  f32x4 acc[4][NT] = {};

  stage(0, 0);
#pragma unroll 1
  for (int k0 = 0; k0 < K; k0 += 32) {
    const int buf = (k0 >> 5) & 1;
    __syncthreads();
    if (k0 + 32 < K) stage(buf ^ 1, k0 + 32);
    bf16x8 af[4], bfr[NT];
#pragma unroll
    for (int t = 0; t < 4; t++) af[t] = ld_frag(&As[buf][aoff[t]]);
#pragma unroll
    for (int t = 0; t < NT; t++) bfr[t] = ld_frag(&Bs[buf][boff[t]]);
#pragma unroll
    for (int mt = 0; mt < 4; mt++)
#pragma unroll
      for (int nt = 0; nt < NT; nt++)
        acc[mt][nt] = MFMA16(af[mt], bfr[nt], acc[mt][nt]);
  }

  if (MODE == 1) {
    float bb[NT];
#pragma unroll
    for (int nt = 0; nt < NT; nt++) bb[nt] = bias[n0 + wn * (TN / 2) + nt * 16 + l16];
#pragma unroll
    for (int mt = 0; mt < 4; mt++) {
#pragma unroll
      for (int r = 0; r < 4; r++) {
        int mr = m0 + wm * 64 + mt * 16 + quad * 4 + r;
        float* orow = outF + (long)mr * N + n0 + wn * (TN / 2) + l16;
#pragma unroll
        for (int nt = 0; nt < NT; nt++)
          orow[nt * 16] = acc[mt][nt][r] + bb[nt];
      }
    }
  }
}

// ---------------- flash attention (S^T, LDS-staged K/V, unified) ------------
// grid (L/128, B*H), 4 waves; wave owns 32 q rows (two 16-q sets); 64-key
// chunks over all 2048 keys. P^T bounced through padded LDS. T13 defer-max.
__global__ __launch_bounds__(256, 3) void attn_k(const u16* __restrict__ qd,
                                                 const u16* __restrict__ kd,
                                                 const u16* __restrict__ vTd,
                                                 u16* __restrict__ ctx) {
  __shared__ u16 Ks[2][64 * 64];
  __shared__ u16 Vs[2][64 * 64];
  __shared__ __align__(16) u16 P[4][32][72];  // per-wave P^T bounce
  const int tid = threadIdx.x;
  const int wave = tid >> 6, lane = tid & 63, quad = lane >> 4, l16 = lane & 15;
  const int bh = blockIdx.y;
  const u16* Q = qd + (long)bh * 2048 * 64;
  const u16* Kp = kd + (long)bh * 2048 * 64;
  const u16* Vt = vTd + (long)bh * 64 * 2048;
  const int qbase = blockIdx.x * 128 + wave * 32;

  // Q as B operand: lane holds Q[q=l16][d = quad*8+j], two q-sets x two halves
  bf16x8 qf[2][2];
#pragma unroll
  for (int qs = 0; qs < 2; qs++) {
    qf[qs][0] = ld_frag(Q + (qbase + qs * 16 + l16) * 64 + quad * 8);
    qf[qs][1] = ld_frag(Q + (qbase + qs * 16 + l16) * 64 + 32 + quad * 8);
  }

  f32x4 o[2][4] = {};              // O^T[d = nt*16+quad*4+r][q = l16] per set
  float m[2] = {-1e30f, -1e30f}, l[2] = {0.f, 0.f};

  // staging: issue i covers 8 rows (128B each): r = wave*16 + i*8 + lane/8
  const int srow = lane >> 3;                // 0..7
  const int sx = (lane & 7) ^ srow;          // swizzled source seg (16B units)
  const int kr0 = wave * 16 + srow;
  const int kr1 = wave * 16 + 8 + srow;

  // fragment seg offsets (u16 units): (g ^ (l16&7))*8
  const int fs0 = ((0 * 4 + quad) ^ (l16 & 7)) * 8;
  const int fs1 = ((1 * 4 + quad) ^ (l16 & 7)) * 8;

  auto stage = [&](int buf, int j0) {
    gload16(Kp + (long)(j0 + kr0) * 64 + sx * 8, &Ks[buf][(wave * 2 + 0) * 512]);
    gload16(Kp + (long)(j0 + kr1) * 64 + sx * 8, &Ks[buf][(wave * 2 + 1) * 512]);
    gload16(Vt + (long)kr0 * 2048 + j0 + sx * 8, &Vs[buf][(wave * 2 + 0) * 512]);
    gload16(Vt + (long)kr1 * 2048 + j0 + sx * 8, &Vs[buf][(wave * 2 + 1) * 512]);
  };

  stage(0, 0);

#pragma unroll 1
  for (int j0 = 0; j0 < 2048; j0 += 64) {
    const int buf = (j0 >> 6) & 1;
    __syncthreads();                       // staged chunk visible; prev body done
    if (j0 + 64 < 2048) stage(buf ^ 1, j0 + 64);

    // ---- S^T = K Q^T over 64 keys, both q-sets (K frags shared) ----
    const u16* kb = &Ks[buf][0];
    f32x4 st[2][4];
#pragma unroll
    for (int f = 0; f < 4; f++) {
      bf16x8 k0 = ld_frag(kb + (f * 16 + l16) * 64 + fs0);
      bf16x8 k1 = ld_frag(kb + (f * 16 + l16) * 64 + fs1);
      f32x4 s0 = {}, s1 = {};
      s0 = MFMA16(k0, qf[0][0], s0); s0 = MFMA16(k1, qf[0][1], s0);
      s1 = MFMA16(k0, qf[1][0], s1); s1 = MFMA16(k1, qf[1][1], s1);
      st[0][f] = s0; st[1][f] = s1;
    }

    // ---- online softmax per q-set (T13 defer-max) ----
#pragma unroll
    for (int qs = 0; qs < 2; qs++) {
      float mx = -1e30f;
#pragma unroll
      for (int f = 0; f < 4; f++)
        mx = fmaxf(mx, fmaxf(fmaxf(st[qs][f][0], st[qs][f][1]),
                             fmaxf(st[qs][f][2], st[qs][f][3])));
      mx = fmaxf(mx, __shfl_xor(mx, 16));
      mx = fmaxf(mx, __shfl_xor(mx, 32));
      if (__any(mx > m[qs] + 8.0f)) {      // skip rescale for small growth
        float mn = fmaxf(m[qs], mx);
        float al = fexp2(m[qs] - mn);
        m[qs] = mn;
        l[qs] *= al;
#pragma unroll
        for (int nt = 0; nt < 4; nt++) {
          o[qs][nt][0] *= al; o[qs][nt][1] *= al;
          o[qs][nt][2] *= al; o[qs][nt][3] *= al;
        }
      }
      float sm = 0.f;
      u16* prow = &P[wave][qs * 16 + l16][0];
#pragma unroll
      for (int f = 0; f < 4; f++) {
        float p0 = fexp2(st[qs][f][0] - m[qs]);
        float p1 = fexp2(st[qs][f][1] - m[qs]);
        float p2 = fexp2(st[qs][f][2] - m[qs]);
        float p3 = fexp2(st[qs][f][3] - m[qs]);
        sm += (p0 + p1) + (p2 + p3);
        uint2 u;
        u.x = packtrunc(p0, p1);
        u.y = packtrunc(p2, p3);
        *(uint2*)(prow + f * 16 + quad * 4) = u;
      }
      sm += __shfl_xor(sm, 16);
      sm += __shfl_xor(sm, 32);
      l[qs] += sm;
    }
    // wave-internal write->read ordering (no inter-wave dep, no barrier)
    __asm__ volatile("s_waitcnt lgkmcnt(0)" ::: "memory");

    // ---- O^T += V^T P^T (V frags shared across q-sets) ----
    const u16* vb = &Vs[buf][0];
    bf16x8 vf[4][2];
#pragma unroll
    for (int nt = 0; nt < 4; nt++) {
      vf[nt][0] = ld_frag(vb + (nt * 16 + l16) * 64 + fs0);
      vf[nt][1] = ld_frag(vb + (nt * 16 + l16) * 64 + fs1);
    }
#pragma unroll
    for (int qs = 0; qs < 2; qs++) {
      const u16* prow = &P[wave][qs * 16 + l16][0];
#pragma unroll
      for (int kh = 0; kh < 2; kh++) {
        bf16x8 pf = ld_frag(prow + kh * 32 + quad * 8);
#pragma unroll
        for (int nt = 0; nt < 4; nt++)
          o[qs][nt] = MFMA16(vf[nt][kh], pf, o[qs][nt]);
      }
    }
  }

  // ---- epilogue: divide by l, write ctx[b][l][h*64+d] ----
  const int bI = bh >> 4, hh = bh & 15;
#pragma unroll
  for (int qs = 0; qs < 2; qs++) {
    const float rl = 1.0f / l[qs];
    const long row = (long)(bI * 2048 + qbase + qs * 16 + l16);
#pragma unroll
    for (int nt = 0; nt < 4; nt++) {
      ushort4 w;
      w.x = f2bf(o[qs][nt][0] * rl);
      w.y = f2bf(o[qs][nt][1] * rl);
      w.z = f2bf(o[qs][nt][2] * rl);
      w.w = f2bf(o[qs][nt][3] * rl);
      *(ushort4*)(ctx + row * 1024 + hh * 64 + nt * 16 + quad * 4) = w;
    }
  }
}

// ---------------- residual + LayerNorm -------------------------------------
__global__ __launch_bounds__(256) void ln_k(const float* __restrict__ a,
                                            const float* __restrict__ b,
                                            const float* __restrict__ g,
                                            const float* __restrict__ be,
                                            float* __restrict__ outF,
                                            u16* __restrict__ outB) {
  const int row = blockIdx.x, tid = threadIdx.x;
  const float* pa = a + (long)row * 1024;
  const float* pb = b + (long)row * 1024;
  float v[4], s = 0.f, sq = 0.f;
#pragma unroll
  for (int i = 0; i < 4; i++) {
    int c = i * 256 + tid;
    v[i] = pa[c] + pb[c];
    s += v[i];
    sq += v[i] * v[i];
  }
#pragma unroll
  for (int off = 1; off < 64; off <<= 1) {
    s += __shfl_xor(s, off);
    sq += __shfl_xor(sq, off);
  }
  __shared__ float red[10];
  int wave = tid >> 6, lane = tid & 63;
  if (lane == 0) { red[wave * 2] = s; red[wave * 2 + 1] = sq; }
  __syncthreads();
  if (tid == 0) {
    float S = red[0] + red[2] + red[4] + red[6];
    float Q = red[1] + red[3] + red[5] + red[7];
    float mu = S * (1.0f / 1024.0f);
    float var = Q * (1.0f / 1024.0f) - mu * mu;
    red[8] = mu;
    red[9] = rsqrtf(var + 1e-5f);
  }
  __syncthreads();
  float mu = red[8], rstd = red[9];
#pragma unroll
  for (int i = 0; i < 4; i++) {
    int c = i * 256 + tid;
    float o = (v[i] - mu) * rstd * g[c] + be[c];
    outF[(long)row * 1024 + c] = o;
    if (outB) outB[(long)row * 1024 + c] = f2bf(o);
  }
}

// ---- residual + 2-slab split-K reduce + bias + LayerNorm (LN2) ------------
__global__ __launch_bounds__(256) void ln2s_k(const float* __restrict__ a,
                                              const float* __restrict__ q0,
                                              const float* __restrict__ q1,
                                              const float* __restrict__ bias,
                                              const float* __restrict__ g,
                                              const float* __restrict__ be,
                                              float* __restrict__ outF) {
  const int row = blockIdx.x, tid = threadIdx.x;
  const long base = (long)row * 1024;
  float v[4], s = 0.f, sq = 0.f;
#pragma unroll
  for (int i = 0; i < 4; i++) {
    int c = i * 256 + tid;
    float ff = q0[base + c] + q1[base + c] + bias[c];
    v[i] = a[base + c] + ff;
    s += v[i];
    sq += v[i] * v[i];
  }
#pragma unroll
  for (int off = 1; off < 64; off <<= 1) {
    s += __shfl_xor(s, off);
    sq += __shfl_xor(sq, off);
  }
  __shared__ float red[10];
  int wave = tid >> 6, lane = tid & 63;
  if (lane == 0) { red[wave * 2] = s; red[wave * 2 + 1] = sq; }
  __syncthreads();
  if (tid == 0) {
    float S = red[0] + red[2] + red[4] + red[6];
    float Q = red[1] + red[3] + red[5] + red[7];
    float mu = S * (1.0f / 1024.0f);
    float var = Q * (1.0f / 1024.0f) - mu * mu;
    red[8] = mu;
    red[9] = rsqrtf(var + 1e-5f);
  }
  __syncthreads();
  float mu = red[8], rstd = red[9];
#pragma unroll
  for (int i = 0; i < 4; i++) {
    int c = i * 256 + tid;
    outF[base + c] = (v[i] - mu) * rstd * g[c] + be[c];
  }
}

// ---------------------------------------------------------------------------
extern "C" void kernel_launch(void* const* d_in, const int* in_sizes, int n_in,
                              void* d_out, int out_size, void* d_ws, size_t ws_size,
                              hipStream_t stream) {
  const float* x  = (const float*)d_in[0];
  const float* Wq = (const float*)d_in[1];  const float* bq = (const float*)d_in[2];
  const float* Wk = (const float*)d_in[3];  const float* bk = (const float*)d_in[4];
  const float* Wv = (const float*)d_in[5];  const float* bv = (const float*)d_in[6];
  const float* Wo = (const float*)d_in[7];  const float* bo = (const float*)d_in[8];
  const float* W1 = (const float*)d_in[9];  const float* b1 = (const float*)d_in[10];
  const float* W2 = (const float*)d_in[11]; const float* b2 = (const float*)d_in[12];
  const float* g1 = (const float*)d_in[13]; const float* be1 = (const float*)d_in[14];
  const float* g2 = (const float*)d_in[15]; const float* be2 = (const float*)d_in[16];

  char* ws = (char*)d_ws;
  size_t off = 0;
  auto alloc = [&](size_t bytes) {
    size_t o = off;
    off += (bytes + 255) & ~(size_t)255;
    return o;
  };
  u16*   xb     = (u16*)(ws + alloc(4096UL * 1024 * 2));
  u16*   wqkvT  = (u16*)(ws + alloc(3072UL * 1024 * 2));
  u16*   woT    = (u16*)(ws + alloc(1024UL * 1024 * 2));
  u16*   w1T    = (u16*)(ws + alloc(4096UL * 1024 * 2));
  u16*   w2T    = (u16*)(ws + alloc(1024UL * 4096 * 2));
  u16*   qb     = (u16*)(ws + alloc(32UL * 2048 * 64 * 2));   // 8 MiB
  u16*   kb     = (u16*)(ws + alloc(32UL * 2048 * 64 * 2));   // 8 MiB
  u16*   vTb    = (u16*)(ws + alloc(32UL * 64 * 2048 * 2));   // 8 MiB
  u16*   ctx    = (u16*)(ws + alloc(4096UL * 1024 * 2));      // 8 MiB
  float* attnO  = (float*)(ws + alloc(4096UL * 1024 * 4));    // 16 MiB
  float* h      = (float*)(ws + alloc(4096UL * 1024 * 4));    // 16 MiB
  u16*   hb     = (u16*)(ws + alloc(4096UL * 1024 * 2));      // 8 MiB
  u16*   ff1    = (u16*)(ws + alloc(4096UL * 4096 * 2));      // 32 MiB
  float* ff2    = (float*)(ws + alloc(4096UL * 1024 * 4));    // 16 MiB
  if (off > ws_size) return;  // workspace too small: bail (bench will flag)

  // FFN-down split-K=2 slabs (regions dead during step 7):
  float* sl0 = ff2;
  float* sl1 = attnO;

  // 1) bf16 conversions / weight transposes
  cvt_bf16_k<<<4096, 256, 0, stream>>>(x, xb);
  transpose4_bf16_k<<<dim3(32, 32, 4), 256, 0, stream>>>(Wq, Wk, Wv, Wo, wqkvT, woT);
  transpose_bf16_k<<<dim3(128, 32), 256, 0, stream>>>(W1, w1T, 1024, 4096);
  transpose_bf16_k<<<dim3(32, 128), 256, 0, stream>>>(W2, w2T, 4096, 1024);

  // 2) QKV projection: 128^2 ring-3, 768 blocks (3/CU), scatter epilogue
  gemm128_k<0><<<dim3(24, 32), 256, 0, stream>>>(
      xb, wqkvT, 3072, 1024, 1024, 1024,
      nullptr, nullptr, nullptr, nullptr,
      qb, kb, vTb, bq, bk, bv);
  // 3) attention: unified (no split), direct ctx write
  attn_k<<<dim3(16, 32), 256, 0, stream>>>(qb, kb, vTb, ctx);
  // 4) output projection (legacy TN=64 kernel)
  gemm_k<1, 64><<<dim3(16, 32), 256, 0, stream>>>(ctx, woT, 4096, 1024, 1024,
                                                  bo, attnO);
  // 5) residual + LN1 (fp32 h + bf16 hb)
  ln_k<<<4096, 256, 0, stream>>>(x, attnO, g1, be1, h, hb);
  // 6) FFN up + GELU: 128^2 ring-3, 1024 blocks (3/CU)
  gemm128_k<2><<<dim3(32, 32), 256, 0, stream>>>(
      hb, w1T, 4096, 1024, 1024, 1024,
      b1, nullptr, ff1, nullptr,
      nullptr, nullptr, nullptr, nullptr, nullptr, nullptr);
  // 7) FFN down: 128^2 ring-3, split-K=2 (Kc=2048), 512 blocks
  gemm128_k<3><<<dim3(8, 32, 2), 256, 0, stream>>>(
      ff1, w2T, 1024, 4096, 4096, 2048,
      nullptr, sl0, nullptr, sl1,
      nullptr, nullptr, nullptr, nullptr, nullptr, nullptr);
  // 8) residual + 2-slab reduce + b2 + LN2 -> out
  ln2s_k<<<4096, 256, 0, stream>>>(h, sl0, sl1, b2, g2, be2, (float*)d_out);
}